// Round 1
// baseline (719.150 us; speedup 1.0000x reference)
//
#include <hip/hip_runtime.h>

#define EPS 1e-5f

typedef __attribute__((ext_vector_type(8))) short s16x8;
typedef __attribute__((ext_vector_type(4))) float f4;

__device__ __forceinline__ short f2bf(float f) {
  union { float f; unsigned u; } x; x.f = f;
  unsigned r = x.u + 0x7fffu + ((x.u >> 16) & 1u);
  return (short)(r >> 16);
}
__device__ __forceinline__ float bf2f(short s) {
  union { unsigned u; float f; } x; x.u = ((unsigned)(unsigned short)s) << 16;
  return x.f;
}

// ---------------------------------------------------------------------------
// GEMM1: C(16384x3072) = x(16384x1024) @ Wqkv(1024x3072), fp32 in, bf16 MFMA,
// epilogue scatters into q/k/v buffers laid out [B][H][L][DK] bf16.
// Tile 128x128, BK=32, 4 waves each computing a 64x64 quadrant (4x4 MFMA tiles).
// ---------------------------------------------------------------------------
__global__ __launch_bounds__(256) void gemm_qkv(
    const float* __restrict__ A, const float* __restrict__ B,
    short* __restrict__ qb, short* __restrict__ kb, short* __restrict__ vb)
{
  __shared__ __align__(16) short As[128 * 40];   // [m][k], pad 32->40 breaks bank aliasing
  __shared__ __align__(16) short Bs[128 * 40];   // transposed: [n][k]
  const int n0 = blockIdx.x * 128;
  const int m0 = blockIdx.y * 128;
  const int tid = threadIdx.x;
  const int w = tid >> 6, lane = tid & 63, quad = lane >> 4, l16 = lane & 15;
  const int wm = (w >> 1) << 6, wn = (w & 1) << 6;

  f4 acc[4][4];
  #pragma unroll
  for (int i = 0; i < 4; i++)
    #pragma unroll
    for (int j = 0; j < 4; j++) acc[i][j] = {0.f, 0.f, 0.f, 0.f};

  const int arow = tid >> 1, aseg = (tid & 1) << 4;   // A: 128 rows x 32 k, 16 f32/thread
  const int brow = tid >> 3, bseg = (tid & 7) << 4;   // B: 32 k-rows x 128 n, 16 f32/thread

  for (int k0 = 0; k0 < 1024; k0 += 32) {
    __syncthreads();
    { // stage A (convert fp32 -> bf16)
      const float4* ap = reinterpret_cast<const float4*>(A + (size_t)(m0 + arow) * 1024 + k0 + aseg);
      union { float4 v[4]; float f[16]; } af;
      af.v[0] = ap[0]; af.v[1] = ap[1]; af.v[2] = ap[2]; af.v[3] = ap[3];
      union { float4 v[2]; short s[16]; } ao;
      #pragma unroll
      for (int i = 0; i < 16; i++) ao.s[i] = f2bf(af.f[i]);
      float4* dst = reinterpret_cast<float4*>(&As[arow * 40 + aseg]);
      dst[0] = ao.v[0]; dst[1] = ao.v[1];
    }
    { // stage B transposed (scalar scatter, correctness-first)
      const float4* bp = reinterpret_cast<const float4*>(B + (size_t)(k0 + brow) * 3072 + n0 + bseg);
      union { float4 v[4]; float f[16]; } bu;
      bu.v[0] = bp[0]; bu.v[1] = bp[1]; bu.v[2] = bp[2]; bu.v[3] = bp[3];
      #pragma unroll
      for (int i = 0; i < 16; i++) Bs[(bseg + i) * 40 + brow] = f2bf(bu.f[i]);
    }
    __syncthreads();
    s16x8 afr[4], bfr[4];
    #pragma unroll
    for (int t = 0; t < 4; t++)
      afr[t] = *reinterpret_cast<const s16x8*>(&As[(wm + t * 16 + l16) * 40 + quad * 8]);
    #pragma unroll
    for (int t = 0; t < 4; t++)
      bfr[t] = *reinterpret_cast<const s16x8*>(&Bs[(wn + t * 16 + l16) * 40 + quad * 8]);
    #pragma unroll
    for (int ti = 0; ti < 4; ti++)
      #pragma unroll
      for (int tj = 0; tj < 4; tj++)
        acc[ti][tj] = __builtin_amdgcn_mfma_f32_16x16x32_bf16(afr[ti], bfr[tj], acc[ti][tj], 0, 0, 0);
  }
  // epilogue: n-tile (128) never crosses the q/k/v 1024-col section boundary
  const int sq = n0 >> 10;
  short* dbuf = (sq == 0) ? qb : (sq == 1) ? kb : vb;
  #pragma unroll
  for (int ti = 0; ti < 4; ti++)
    #pragma unroll
    for (int tj = 0; tj < 4; tj++)
      #pragma unroll
      for (int r = 0; r < 4; r++) {
        int i = m0 + wm + ti * 16 + quad * 4 + r;       // C/D row = quad*4+reg  [m89]
        int j = n0 + wn + tj * 16 + l16;                // C/D col = lane&15
        int hh = (j >> 6) & 15, dd = j & 63;
        int bb = i >> 12, ll = i & 4095;
        dbuf[(((size_t)(bb * 16 + hh)) * 4096 + ll) * 64 + dd] = f2bf(acc[ti][tj][r]);
      }
}

// ---------------------------------------------------------------------------
// LayerNorm (no affine) over each 64-elem head row of k, in place. 1 wave/row.
// ---------------------------------------------------------------------------
__global__ __launch_bounds__(256) void ln_k(short* __restrict__ kbuf)
{
  const int row = blockIdx.x * 4 + (threadIdx.x >> 6);
  const int lane = threadIdx.x & 63;
  const size_t idx = (size_t)row * 64 + lane;
  float v = bf2f(kbuf[idx]);
  float s = v, s2 = v * v;
  #pragma unroll
  for (int off = 32; off; off >>= 1) {
    s += __shfl_xor(s, off);
    s2 += __shfl_xor(s2, off);
  }
  float mean = s * (1.f / 64.f);
  float var = s2 * (1.f / 64.f) - mean * mean;
  float rstd = rsqrtf(var + EPS);
  kbuf[idx] = f2bf((v - mean) * rstd);
}

// ---------------------------------------------------------------------------
// Chunked linear-attention scan. One block per (b,h); 64 sequential chunks.
// 4 waves; wave w owns output columns [w*16, w*16+16) (tile-col stripe).
// S state (64x64 fp32) lives in accS registers (C-layout stripes), re-emitted
// to LDS as bf16 each chunk for the inter matmul's B operand.
// ---------------------------------------------------------------------------
__global__ __launch_bounds__(256) void scan_chunks(
    const short* __restrict__ qb, const short* __restrict__ kb,
    const short* __restrict__ vb, short* __restrict__ yb)
{
  __shared__ __align__(16) short qs[64 * 72];  // q[t][d]
  __shared__ __align__(16) short ks[64 * 72];  // k[t][d]
  __shared__ __align__(16) short kT[64 * 72];  // k^T[e][t]
  __shared__ __align__(16) short vT[64 * 72];  // v^T[d][t]
  __shared__ __align__(16) short Sb[64 * 72];  // S[d][e] bf16 (pre-update)
  __shared__ __align__(16) short Ps[64 * 72];  // masked scores [t][s]

  const int bh = blockIdx.x;
  const int b = bh >> 4, h = bh & 15;
  const int tid = threadIdx.x;
  const int w = tid >> 6, lane = tid & 63, quad = lane >> 4, l16 = lane & 15;
  const int srow = tid >> 2, sseg = (tid & 3) << 4;
  const size_t base = (size_t)bh * 4096 * 64;

  f4 accS[4];
  #pragma unroll
  for (int i = 0; i < 4; i++) accS[i] = {0.f, 0.f, 0.f, 0.f};

  for (int c = 0; c < 64; c++) {
    __syncthreads();
    { // stage q,k,v chunk (bf16); build kT, vT transposes
      size_t g = base + ((size_t)(c * 64 + srow)) * 64 + sseg;
      const float4* qp = reinterpret_cast<const float4*>(qb + g);
      float4 q0 = qp[0], q1 = qp[1];
      *reinterpret_cast<float4*>(&qs[srow * 72 + sseg]) = q0;
      *reinterpret_cast<float4*>(&qs[srow * 72 + sseg + 8]) = q1;
      const float4* kp = reinterpret_cast<const float4*>(kb + g);
      union { float4 v[2]; short s[16]; } ku;
      ku.v[0] = kp[0]; ku.v[1] = kp[1];
      *reinterpret_cast<float4*>(&ks[srow * 72 + sseg]) = ku.v[0];
      *reinterpret_cast<float4*>(&ks[srow * 72 + sseg + 8]) = ku.v[1];
      #pragma unroll
      for (int i = 0; i < 16; i++) kT[(sseg + i) * 72 + srow] = ku.s[i];
      const float4* vp = reinterpret_cast<const float4*>(vb + g);
      union { float4 v[2]; short s[16]; } vu;
      vu.v[0] = vp[0]; vu.v[1] = vp[1];
      #pragma unroll
      for (int i = 0; i < 16; i++) vT[(sseg + i) * 72 + srow] = vu.s[i];
    }
    // emit pre-update S to LDS (chunk 0: zeros)
    #pragma unroll
    for (int ti = 0; ti < 4; ti++)
      #pragma unroll
      for (int r = 0; r < 4; r++)
        Sb[(ti * 16 + quad * 4 + r) * 72 + w * 16 + l16] = f2bf(accS[ti][r]);
    __syncthreads();

    // q A-fragments (shared by scores and inter)
    s16x8 qa[4][2];
    #pragma unroll
    for (int ti = 0; ti < 4; ti++)
      #pragma unroll
      for (int kh = 0; kh < 2; kh++)
        qa[ti][kh] = *reinterpret_cast<const s16x8*>(&qs[(ti * 16 + l16) * 72 + kh * 32 + quad * 8]);

    // scores[t][s] = sum_d q[t,d] k[s,d], causal tril (s<=t)
    s16x8 kf[2];
    #pragma unroll
    for (int kh = 0; kh < 2; kh++)
      kf[kh] = *reinterpret_cast<const s16x8*>(&ks[(w * 16 + l16) * 72 + kh * 32 + quad * 8]);
    #pragma unroll
    for (int ti = 0; ti < 4; ti++) {
      f4 z = {0.f, 0.f, 0.f, 0.f};
      z = __builtin_amdgcn_mfma_f32_16x16x32_bf16(qa[ti][0], kf[0], z, 0, 0, 0);
      z = __builtin_amdgcn_mfma_f32_16x16x32_bf16(qa[ti][1], kf[1], z, 0, 0, 0);
      #pragma unroll
      for (int r = 0; r < 4; r++) {
        int t = ti * 16 + quad * 4 + r;
        int s = w * 16 + l16;
        Ps[t * 72 + s] = (s <= t) ? f2bf(z[r]) : (short)0;
      }
    }
    __syncthreads();

    // y[t][d] = sum_s P[t,s] v[s,d]  +  sum_e q[t,e] S[d,e]
    s16x8 vf[2], sf[2];
    #pragma unroll
    for (int kh = 0; kh < 2; kh++) {
      vf[kh] = *reinterpret_cast<const s16x8*>(&vT[(w * 16 + l16) * 72 + kh * 32 + quad * 8]);
      sf[kh] = *reinterpret_cast<const s16x8*>(&Sb[(w * 16 + l16) * 72 + kh * 32 + quad * 8]);
    }
    #pragma unroll
    for (int ti = 0; ti < 4; ti++) {
      f4 z = {0.f, 0.f, 0.f, 0.f};
      s16x8 p0 = *reinterpret_cast<const s16x8*>(&Ps[(ti * 16 + l16) * 72 + quad * 8]);
      s16x8 p1 = *reinterpret_cast<const s16x8*>(&Ps[(ti * 16 + l16) * 72 + 32 + quad * 8]);
      z = __builtin_amdgcn_mfma_f32_16x16x32_bf16(p0, vf[0], z, 0, 0, 0);
      z = __builtin_amdgcn_mfma_f32_16x16x32_bf16(p1, vf[1], z, 0, 0, 0);
      z = __builtin_amdgcn_mfma_f32_16x16x32_bf16(qa[ti][0], sf[0], z, 0, 0, 0);
      z = __builtin_amdgcn_mfma_f32_16x16x32_bf16(qa[ti][1], sf[1], z, 0, 0, 0);
      #pragma unroll
      for (int r = 0; r < 4; r++) {
        int t = ti * 16 + quad * 4 + r;
        int d = w * 16 + l16;
        yb[(((size_t)b * 4096) + c * 64 + t) * 1024 + h * 64 + d] = f2bf(z[r]);
      }
    }

    // S[d,e] += sum_t v[t,d] k[t,e]   (A = vT rows, B = kT rows)
    s16x8 ku0 = *reinterpret_cast<const s16x8*>(&kT[(w * 16 + l16) * 72 + quad * 8]);
    s16x8 ku1 = *reinterpret_cast<const s16x8*>(&kT[(w * 16 + l16) * 72 + 32 + quad * 8]);
    #pragma unroll
    for (int ti = 0; ti < 4; ti++) {
      s16x8 va0 = *reinterpret_cast<const s16x8*>(&vT[(ti * 16 + l16) * 72 + quad * 8]);
      s16x8 va1 = *reinterpret_cast<const s16x8*>(&vT[(ti * 16 + l16) * 72 + 32 + quad * 8]);
      accS[ti] = __builtin_amdgcn_mfma_f32_16x16x32_bf16(va0, ku0, accS[ti], 0, 0, 0);
      accS[ti] = __builtin_amdgcn_mfma_f32_16x16x32_bf16(va1, ku1, accS[ti], 0, 0, 0);
    }
  }
}

// ---------------------------------------------------------------------------
// GEMM2: out(16384x1024 fp32) = y(16384x1024 bf16) @ Wo(1024x1024 fp32->bf16)
// ---------------------------------------------------------------------------
__global__ __launch_bounds__(256) void gemm_out(
    const short* __restrict__ A, const float* __restrict__ B, float* __restrict__ C)
{
  __shared__ __align__(16) short As[128 * 40];
  __shared__ __align__(16) short Bs[128 * 40];   // transposed [n][k]
  const int n0 = blockIdx.x * 128;
  const int m0 = blockIdx.y * 128;
  const int tid = threadIdx.x;
  const int w = tid >> 6, lane = tid & 63, quad = lane >> 4, l16 = lane & 15;
  const int wm = (w >> 1) << 6, wn = (w & 1) << 6;

  f4 acc[4][4];
  #pragma unroll
  for (int i = 0; i < 4; i++)
    #pragma unroll
    for (int j = 0; j < 4; j++) acc[i][j] = {0.f, 0.f, 0.f, 0.f};

  const int arow = tid >> 1, aseg = (tid & 1) << 4;   // 16 bf16 per thread
  const int brow = tid >> 3, bseg = (tid & 7) << 4;

  for (int k0 = 0; k0 < 1024; k0 += 32) {
    __syncthreads();
    { // stage A (already bf16)
      const float4* ap = reinterpret_cast<const float4*>(A + (size_t)(m0 + arow) * 1024 + k0 + aseg);
      float4 a0 = ap[0], a1 = ap[1];
      float4* dst = reinterpret_cast<float4*>(&As[arow * 40 + aseg]);
      dst[0] = a0; dst[1] = a1;
    }
    { // stage B transposed
      const float4* bp = reinterpret_cast<const float4*>(B + (size_t)(k0 + brow) * 1024 + n0 + bseg);
      union { float4 v[4]; float f[16]; } bu;
      bu.v[0] = bp[0]; bu.v[1] = bp[1]; bu.v[2] = bp[2]; bu.v[3] = bp[3];
      #pragma unroll
      for (int i = 0; i < 16; i++) Bs[(bseg + i) * 40 + brow] = f2bf(bu.f[i]);
    }
    __syncthreads();
    s16x8 afr[4], bfr[4];
    #pragma unroll
    for (int t = 0; t < 4; t++)
      afr[t] = *reinterpret_cast<const s16x8*>(&As[(wm + t * 16 + l16) * 40 + quad * 8]);
    #pragma unroll
    for (int t = 0; t < 4; t++)
      bfr[t] = *reinterpret_cast<const s16x8*>(&Bs[(wn + t * 16 + l16) * 40 + quad * 8]);
    #pragma unroll
    for (int ti = 0; ti < 4; ti++)
      #pragma unroll
      for (int tj = 0; tj < 4; tj++)
        acc[ti][tj] = __builtin_amdgcn_mfma_f32_16x16x32_bf16(afr[ti], bfr[tj], acc[ti][tj], 0, 0, 0);
  }
  #pragma unroll
  for (int ti = 0; ti < 4; ti++)
    #pragma unroll
    for (int tj = 0; tj < 4; tj++)
      #pragma unroll
      for (int r = 0; r < 4; r++) {
        int i = m0 + wm + ti * 16 + quad * 4 + r;
        int j = n0 + wn + tj * 16 + l16;
        C[(size_t)i * 1024 + j] = acc[ti][tj][r];
      }
}

extern "C" void kernel_launch(void* const* d_in, const int* in_sizes, int n_in,
                              void* d_out, int out_size, void* d_ws, size_t ws_size,
                              hipStream_t stream) {
  const float* x    = (const float*)d_in[0];   // (4,4096,1024) fp32
  const float* Wqkv = (const float*)d_in[1];   // (1024,3072) fp32
  const float* Wo   = (const float*)d_in[2];   // (1024,1024) fp32
  float* out = (float*)d_out;                  // (4,4096,1024) fp32

  // workspace: q,k,v [B][H][L][DK] bf16 (32 MB each) + y [B][L][D] bf16 (32 MB)
  short* qb = (short*)d_ws;
  short* kb = qb + (size_t)16777216;
  short* vb = kb + (size_t)16777216;
  short* yb = vb + (size_t)16777216;

  gemm_qkv   <<<dim3(24, 128), 256, 0, stream>>>(x, Wqkv, qb, kb, vb);
  ln_k       <<<dim3(65536),   256, 0, stream>>>(kb);
  scan_chunks<<<dim3(64),      256, 0, stream>>>(qb, kb, vb, yb);
  gemm_out   <<<dim3(8, 128),  256, 0, stream>>>(yb, Wo, out);
}

// Round 2
// 467.706 us; speedup vs baseline: 1.5376x; 1.5376x over previous
//
#include <hip/hip_runtime.h>

#define EPS 1e-5f

typedef __attribute__((ext_vector_type(8))) short s16x8;
typedef __attribute__((ext_vector_type(4))) float f4;

__device__ __forceinline__ short f2bf(float f) {
  union { float f; unsigned u; } x; x.f = f;
  unsigned r = x.u + 0x7fffu + ((x.u >> 16) & 1u);
  return (short)(r >> 16);
}
__device__ __forceinline__ float bf2f(short s) {
  union { unsigned u; float f; } x; x.u = ((unsigned)(unsigned short)s) << 16;
  return x.f;
}
// async global->LDS, 16B per lane; lds dest must be wave-uniform base (+lane*16 implicit)
__device__ __forceinline__ void gll16(const short* g, short* l) {
  __builtin_amdgcn_global_load_lds((const __attribute__((address_space(1))) void*)g,
                                   (__attribute__((address_space(3))) void*)l, 16, 0, 0);
}

// ---------------------------------------------------------------------------
// Transpose+cast: WT[n][k] (bf16) = W[k][n] (fp32). 32x32 tiles.
// ---------------------------------------------------------------------------
__global__ __launch_bounds__(256) void transpose_cast(
    const float* __restrict__ W, short* __restrict__ WT, int K, int N)
{
  __shared__ float tile[32][33];
  const int n0 = blockIdx.x * 32, k0 = blockIdx.y * 32;
  const int tx = threadIdx.x & 31, ty = threadIdx.x >> 5;
  #pragma unroll
  for (int i = 0; i < 4; i++) {
    int r = ty + i * 8;
    tile[r][tx] = W[(size_t)(k0 + r) * N + n0 + tx];
  }
  __syncthreads();
  #pragma unroll
  for (int i = 0; i < 4; i++) {
    int r = ty + i * 8;
    WT[(size_t)(n0 + r) * K + k0 + tx] = f2bf(tile[tx][r]);
  }
}

// ---------------------------------------------------------------------------
// GEMM1 v2: C(16384x3072) = x(16384x1024 fp32) @ WqkvT^T; B staged via
// global_load_lds from pre-transposed bf16 WqkvT[n][k]; A converted in-reg.
// Epilogue scatters q/k/v [B][H][L][DK] bf16.
// ---------------------------------------------------------------------------
__global__ __launch_bounds__(256) void gemm_qkv_v2(
    const float* __restrict__ A, const short* __restrict__ BT,
    short* __restrict__ qb, short* __restrict__ kb, short* __restrict__ vb)
{
  __shared__ __align__(16) short As[128 * 40];   // padded (VGPR-staged)
  __shared__ __align__(16) short Bs[128 * 32];   // unpadded (global_load_lds)
  const int n0 = blockIdx.x * 128;
  const int m0 = blockIdx.y * 128;
  const int tid = threadIdx.x;
  const int w = tid >> 6, lane = tid & 63, quad = lane >> 4, l16 = lane & 15;
  const int wm = (w >> 1) << 6, wn = (w & 1) << 6;

  f4 acc[4][4];
  #pragma unroll
  for (int i = 0; i < 4; i++)
    #pragma unroll
    for (int j = 0; j < 4; j++) acc[i][j] = {0.f, 0.f, 0.f, 0.f};

  const int arow = tid >> 1, aseg = (tid & 1) << 4;
  const int brow = w * 32 + (lane >> 2), bofs = (lane & 3) << 3;  // 16 rows/instr

  for (int k0 = 0; k0 < 1024; k0 += 32) {
    __syncthreads();
    // B: async global->LDS (2x16 rows per wave)
    gll16(BT + (size_t)(n0 + brow) * 1024 + k0 + bofs, &Bs[(w * 32) * 32]);
    gll16(BT + (size_t)(n0 + brow + 16) * 1024 + k0 + bofs, &Bs[(w * 32 + 16) * 32]);
    // A: fp32 load + convert + LDS store
    {
      const float4* ap = reinterpret_cast<const float4*>(A + (size_t)(m0 + arow) * 1024 + k0 + aseg);
      union { float4 v[4]; float f[16]; } af;
      af.v[0] = ap[0]; af.v[1] = ap[1]; af.v[2] = ap[2]; af.v[3] = ap[3];
      union { float4 v[2]; short s[16]; } ao;
      #pragma unroll
      for (int i = 0; i < 16; i++) ao.s[i] = f2bf(af.f[i]);
      float4* dst = reinterpret_cast<float4*>(&As[arow * 40 + aseg]);
      dst[0] = ao.v[0]; dst[1] = ao.v[1];
    }
    __syncthreads();
    s16x8 afr[4], bfr[4];
    #pragma unroll
    for (int t = 0; t < 4; t++)
      afr[t] = *reinterpret_cast<const s16x8*>(&As[(wm + t * 16 + l16) * 40 + quad * 8]);
    #pragma unroll
    for (int t = 0; t < 4; t++)
      bfr[t] = *reinterpret_cast<const s16x8*>(&Bs[(wn + t * 16 + l16) * 32 + quad * 8]);
    #pragma unroll
    for (int ti = 0; ti < 4; ti++)
      #pragma unroll
      for (int tj = 0; tj < 4; tj++)
        acc[ti][tj] = __builtin_amdgcn_mfma_f32_16x16x32_bf16(afr[ti], bfr[tj], acc[ti][tj], 0, 0, 0);
  }
  const int sq = n0 >> 10;
  short* dbuf = (sq == 0) ? qb : (sq == 1) ? kb : vb;
  #pragma unroll
  for (int ti = 0; ti < 4; ti++)
    #pragma unroll
    for (int tj = 0; tj < 4; tj++)
      #pragma unroll
      for (int r = 0; r < 4; r++) {
        int i = m0 + wm + ti * 16 + quad * 4 + r;
        int j = n0 + wn + tj * 16 + l16;
        int hh = (j >> 6) & 15, dd = j & 63;
        int bb = i >> 12, ll = i & 4095;
        dbuf[(((size_t)(bb * 16 + hh)) * 4096 + ll) * 64 + dd] = f2bf(acc[ti][tj][r]);
      }
}

// ---------------------------------------------------------------------------
// LayerNorm (no affine) over each 64-elem head row of k, in place.
// ---------------------------------------------------------------------------
__global__ __launch_bounds__(256) void ln_k(short* __restrict__ kbuf)
{
  const int row = blockIdx.x * 4 + (threadIdx.x >> 6);
  const int lane = threadIdx.x & 63;
  const size_t idx = (size_t)row * 64 + lane;
  float v = bf2f(kbuf[idx]);
  float s = v, s2 = v * v;
  #pragma unroll
  for (int off = 32; off; off >>= 1) {
    s += __shfl_xor(s, off);
    s2 += __shfl_xor(s2, off);
  }
  float mean = s * (1.f / 64.f);
  float var = s2 * (1.f / 64.f) - mean * mean;
  float rstd = rsqrtf(var + EPS);
  kbuf[idx] = f2bf((v - mean) * rstd);
}

// ---------------------------------------------------------------------------
// Scan pass A: per-chunk outer product G[bh][c][d][e] = sum_t v[t,d] k[t,e].
// One block per (bh,c) = 4096 blocks.
// ---------------------------------------------------------------------------
__global__ __launch_bounds__(256) void chunk_outer(
    const short* __restrict__ kb, const short* __restrict__ vb,
    short* __restrict__ G)
{
  __shared__ __align__(16) short kT[64 * 72];
  __shared__ __align__(16) short vT[64 * 72];
  const int bh = blockIdx.x >> 6, c = blockIdx.x & 63;
  const int tid = threadIdx.x;
  const int w = tid >> 6, lane = tid & 63, quad = lane >> 4, l16 = lane & 15;
  const int srow = tid >> 2, sseg = (tid & 3) << 4;
  const size_t base = (size_t)bh * 262144 + (size_t)(c * 64 + srow) * 64 + sseg;

  {
    const float4* kp = reinterpret_cast<const float4*>(kb + base);
    union { float4 v[2]; short s[16]; } ku;
    ku.v[0] = kp[0]; ku.v[1] = kp[1];
    #pragma unroll
    for (int i = 0; i < 16; i++) kT[(sseg + i) * 72 + srow] = ku.s[i];
    const float4* vp = reinterpret_cast<const float4*>(vb + base);
    union { float4 v[2]; short s[16]; } vu;
    vu.v[0] = vp[0]; vu.v[1] = vp[1];
    #pragma unroll
    for (int i = 0; i < 16; i++) vT[(sseg + i) * 72 + srow] = vu.s[i];
  }
  __syncthreads();
  // wave w computes G rows [w*16, w*16+16)
  s16x8 va0 = *reinterpret_cast<const s16x8*>(&vT[(w * 16 + l16) * 72 + quad * 8]);
  s16x8 va1 = *reinterpret_cast<const s16x8*>(&vT[(w * 16 + l16) * 72 + 32 + quad * 8]);
  short* Gc = G + ((size_t)blockIdx.x) * 4096;
  #pragma unroll
  for (int tj = 0; tj < 4; tj++) {
    s16x8 kb0 = *reinterpret_cast<const s16x8*>(&kT[(tj * 16 + l16) * 72 + quad * 8]);
    s16x8 kb1 = *reinterpret_cast<const s16x8*>(&kT[(tj * 16 + l16) * 72 + 32 + quad * 8]);
    f4 z = {0.f, 0.f, 0.f, 0.f};
    z = __builtin_amdgcn_mfma_f32_16x16x32_bf16(va0, kb0, z, 0, 0, 0);
    z = __builtin_amdgcn_mfma_f32_16x16x32_bf16(va1, kb1, z, 0, 0, 0);
    #pragma unroll
    for (int r = 0; r < 4; r++)
      Gc[(w * 16 + quad * 4 + r) * 64 + tj * 16 + l16] = f2bf(z[r]);
  }
}

// ---------------------------------------------------------------------------
// Scan pass B: in-place exclusive prefix over c (fp32 accum, bf16 storage).
// Grid 256 = 64 bh x 4 row-groups; thread owns 4 consecutive elements.
// ---------------------------------------------------------------------------
__global__ __launch_bounds__(256) void prefix_S(short* __restrict__ G)
{
  const int bh = blockIdx.x >> 2, rg = blockIdx.x & 3;
  const size_t base = (size_t)bh * 262144 + rg * 1024 + threadIdx.x * 4;
  float s0 = 0.f, s1 = 0.f, s2 = 0.f, s3 = 0.f;
  for (int c = 0; c < 64; c++) {
    short* p = G + base + (size_t)c * 4096;
    union { uint2 v; short s[4]; } gu;
    gu.v = *reinterpret_cast<const uint2*>(p);
    float g0 = bf2f(gu.s[0]), g1 = bf2f(gu.s[1]), g2 = bf2f(gu.s[2]), g3 = bf2f(gu.s[3]);
    union { uint2 v; short s[4]; } su;
    su.s[0] = f2bf(s0); su.s[1] = f2bf(s1); su.s[2] = f2bf(s2); su.s[3] = f2bf(s3);
    *reinterpret_cast<uint2*>(p) = su.v;
    s0 += g0; s1 += g1; s2 += g2; s3 += g3;
  }
}

// ---------------------------------------------------------------------------
// Scan pass C: per (bh,c) output: y = tril(q k^T) v + q S^T-contract.
// q/k/S fragments straight from global; vT and P via LDS.
// ---------------------------------------------------------------------------
__global__ __launch_bounds__(256) void chunk_out(
    const short* __restrict__ qb, const short* __restrict__ kb,
    const short* __restrict__ vb, const short* __restrict__ S,
    short* __restrict__ yb)
{
  __shared__ __align__(16) short vT[64 * 72];
  __shared__ __align__(16) short Ps[64 * 72];
  const int bh = blockIdx.x >> 6, c = blockIdx.x & 63;
  const int b = bh >> 4, h = bh & 15;
  const int tid = threadIdx.x;
  const int w = tid >> 6, lane = tid & 63, quad = lane >> 4, l16 = lane & 15;
  const int srow = tid >> 2, sseg = (tid & 3) << 4;
  const size_t base = (size_t)bh * 262144 + (size_t)c * 4096;

  { // stage v transposed
    const float4* vp = reinterpret_cast<const float4*>(vb + base + (size_t)srow * 64 + sseg);
    union { float4 v[2]; short s[16]; } vu;
    vu.v[0] = vp[0]; vu.v[1] = vp[1];
    #pragma unroll
    for (int i = 0; i < 16; i++) vT[(sseg + i) * 72 + srow] = vu.s[i];
  }
  // q A-fragments, k B-fragments, S B-fragments direct from global
  s16x8 qa[4][2], kf[2], sf[2];
  #pragma unroll
  for (int ti = 0; ti < 4; ti++)
    #pragma unroll
    for (int kh = 0; kh < 2; kh++)
      qa[ti][kh] = *reinterpret_cast<const s16x8*>(
          qb + base + (size_t)(ti * 16 + l16) * 64 + kh * 32 + quad * 8);
  #pragma unroll
  for (int kh = 0; kh < 2; kh++) {
    kf[kh] = *reinterpret_cast<const s16x8*>(
        kb + base + (size_t)(w * 16 + l16) * 64 + kh * 32 + quad * 8);
    sf[kh] = *reinterpret_cast<const s16x8*>(
        S + base + (size_t)(w * 16 + l16) * 64 + kh * 32 + quad * 8);
  }
  __syncthreads();
  // scores (wave w owns col-stripe s in [w*16, w*16+16))
  #pragma unroll
  for (int ti = 0; ti < 4; ti++) {
    f4 z = {0.f, 0.f, 0.f, 0.f};
    z = __builtin_amdgcn_mfma_f32_16x16x32_bf16(qa[ti][0], kf[0], z, 0, 0, 0);
    z = __builtin_amdgcn_mfma_f32_16x16x32_bf16(qa[ti][1], kf[1], z, 0, 0, 0);
    #pragma unroll
    for (int r = 0; r < 4; r++) {
      int t = ti * 16 + quad * 4 + r;
      int s = w * 16 + l16;
      Ps[t * 72 + s] = (s <= t) ? f2bf(z[r]) : (short)0;
    }
  }
  __syncthreads();
  s16x8 vf0 = *reinterpret_cast<const s16x8*>(&vT[(w * 16 + l16) * 72 + quad * 8]);
  s16x8 vf1 = *reinterpret_cast<const s16x8*>(&vT[(w * 16 + l16) * 72 + 32 + quad * 8]);
  #pragma unroll
  for (int ti = 0; ti < 4; ti++) {
    f4 z = {0.f, 0.f, 0.f, 0.f};
    s16x8 p0 = *reinterpret_cast<const s16x8*>(&Ps[(ti * 16 + l16) * 72 + quad * 8]);
    s16x8 p1 = *reinterpret_cast<const s16x8*>(&Ps[(ti * 16 + l16) * 72 + 32 + quad * 8]);
    z = __builtin_amdgcn_mfma_f32_16x16x32_bf16(p0, vf0, z, 0, 0, 0);
    z = __builtin_amdgcn_mfma_f32_16x16x32_bf16(p1, vf1, z, 0, 0, 0);
    z = __builtin_amdgcn_mfma_f32_16x16x32_bf16(qa[ti][0], sf[0], z, 0, 0, 0);
    z = __builtin_amdgcn_mfma_f32_16x16x32_bf16(qa[ti][1], sf[1], z, 0, 0, 0);
    #pragma unroll
    for (int r = 0; r < 4; r++) {
      int t = ti * 16 + quad * 4 + r;
      int d = w * 16 + l16;
      yb[(((size_t)b * 4096) + c * 64 + t) * 1024 + h * 64 + d] = f2bf(z[r]);
    }
  }
}

// ---------------------------------------------------------------------------
// GEMM2 v2: out(16384x1024 fp32) = y(bf16) @ WoT^T; both operands via
// global_load_lds (full m97 structure).
// ---------------------------------------------------------------------------
__global__ __launch_bounds__(256) void gemm_out_v2(
    const short* __restrict__ A, const short* __restrict__ BT, float* __restrict__ C)
{
  __shared__ __align__(16) short As[128 * 32];
  __shared__ __align__(16) short Bs[128 * 32];
  const int n0 = blockIdx.x * 128;
  const int m0 = blockIdx.y * 128;
  const int tid = threadIdx.x;
  const int w = tid >> 6, lane = tid & 63, quad = lane >> 4, l16 = lane & 15;
  const int wm = (w >> 1) << 6, wn = (w & 1) << 6;

  f4 acc[4][4];
  #pragma unroll
  for (int i = 0; i < 4; i++)
    #pragma unroll
    for (int j = 0; j < 4; j++) acc[i][j] = {0.f, 0.f, 0.f, 0.f};

  const int row = w * 32 + (lane >> 2), ofs = (lane & 3) << 3;

  for (int k0 = 0; k0 < 1024; k0 += 32) {
    __syncthreads();
    gll16(A + (size_t)(m0 + row) * 1024 + k0 + ofs, &As[(w * 32) * 32]);
    gll16(A + (size_t)(m0 + row + 16) * 1024 + k0 + ofs, &As[(w * 32 + 16) * 32]);
    gll16(BT + (size_t)(n0 + row) * 1024 + k0 + ofs, &Bs[(w * 32) * 32]);
    gll16(BT + (size_t)(n0 + row + 16) * 1024 + k0 + ofs, &Bs[(w * 32 + 16) * 32]);
    __syncthreads();
    s16x8 afr[4], bfr[4];
    #pragma unroll
    for (int t = 0; t < 4; t++)
      afr[t] = *reinterpret_cast<const s16x8*>(&As[(wm + t * 16 + l16) * 32 + quad * 8]);
    #pragma unroll
    for (int t = 0; t < 4; t++)
      bfr[t] = *reinterpret_cast<const s16x8*>(&Bs[(wn + t * 16 + l16) * 32 + quad * 8]);
    #pragma unroll
    for (int ti = 0; ti < 4; ti++)
      #pragma unroll
      for (int tj = 0; tj < 4; tj++)
        acc[ti][tj] = __builtin_amdgcn_mfma_f32_16x16x32_bf16(afr[ti], bfr[tj], acc[ti][tj], 0, 0, 0);
  }
  #pragma unroll
  for (int ti = 0; ti < 4; ti++)
    #pragma unroll
    for (int tj = 0; tj < 4; tj++)
      #pragma unroll
      for (int r = 0; r < 4; r++) {
        int i = m0 + wm + ti * 16 + quad * 4 + r;
        int j = n0 + wn + tj * 16 + l16;
        C[(size_t)i * 1024 + j] = acc[ti][tj][r];
      }
}

// ===========================================================================
// Fallback path (round-1 kernels) for ws_size < 168 MB.
// ===========================================================================
__global__ __launch_bounds__(256) void gemm_qkv_r1(
    const float* __restrict__ A, const float* __restrict__ B,
    short* __restrict__ qb, short* __restrict__ kb, short* __restrict__ vb)
{
  __shared__ __align__(16) short As[128 * 40];
  __shared__ __align__(16) short Bs[128 * 40];
  const int n0 = blockIdx.x * 128;
  const int m0 = blockIdx.y * 128;
  const int tid = threadIdx.x;
  const int w = tid >> 6, lane = tid & 63, quad = lane >> 4, l16 = lane & 15;
  const int wm = (w >> 1) << 6, wn = (w & 1) << 6;
  f4 acc[4][4];
  #pragma unroll
  for (int i = 0; i < 4; i++)
    #pragma unroll
    for (int j = 0; j < 4; j++) acc[i][j] = {0.f, 0.f, 0.f, 0.f};
  const int arow = tid >> 1, aseg = (tid & 1) << 4;
  const int brow = tid >> 3, bseg = (tid & 7) << 4;
  for (int k0 = 0; k0 < 1024; k0 += 32) {
    __syncthreads();
    {
      const float4* ap = reinterpret_cast<const float4*>(A + (size_t)(m0 + arow) * 1024 + k0 + aseg);
      union { float4 v[4]; float f[16]; } af;
      af.v[0] = ap[0]; af.v[1] = ap[1]; af.v[2] = ap[2]; af.v[3] = ap[3];
      union { float4 v[2]; short s[16]; } ao;
      #pragma unroll
      for (int i = 0; i < 16; i++) ao.s[i] = f2bf(af.f[i]);
      float4* dst = reinterpret_cast<float4*>(&As[arow * 40 + aseg]);
      dst[0] = ao.v[0]; dst[1] = ao.v[1];
    }
    {
      const float4* bp = reinterpret_cast<const float4*>(B + (size_t)(k0 + brow) * 3072 + n0 + bseg);
      union { float4 v[4]; float f[16]; } bu;
      bu.v[0] = bp[0]; bu.v[1] = bp[1]; bu.v[2] = bp[2]; bu.v[3] = bp[3];
      #pragma unroll
      for (int i = 0; i < 16; i++) Bs[(bseg + i) * 40 + brow] = f2bf(bu.f[i]);
    }
    __syncthreads();
    s16x8 afr[4], bfr[4];
    #pragma unroll
    for (int t = 0; t < 4; t++)
      afr[t] = *reinterpret_cast<const s16x8*>(&As[(wm + t * 16 + l16) * 40 + quad * 8]);
    #pragma unroll
    for (int t = 0; t < 4; t++)
      bfr[t] = *reinterpret_cast<const s16x8*>(&Bs[(wn + t * 16 + l16) * 40 + quad * 8]);
    #pragma unroll
    for (int ti = 0; ti < 4; ti++)
      #pragma unroll
      for (int tj = 0; tj < 4; tj++)
        acc[ti][tj] = __builtin_amdgcn_mfma_f32_16x16x32_bf16(afr[ti], bfr[tj], acc[ti][tj], 0, 0, 0);
  }
  const int sq = n0 >> 10;
  short* dbuf = (sq == 0) ? qb : (sq == 1) ? kb : vb;
  #pragma unroll
  for (int ti = 0; ti < 4; ti++)
    #pragma unroll
    for (int tj = 0; tj < 4; tj++)
      #pragma unroll
      for (int r = 0; r < 4; r++) {
        int i = m0 + wm + ti * 16 + quad * 4 + r;
        int j = n0 + wn + tj * 16 + l16;
        int hh = (j >> 6) & 15, dd = j & 63;
        int bb = i >> 12, ll = i & 4095;
        dbuf[(((size_t)(bb * 16 + hh)) * 4096 + ll) * 64 + dd] = f2bf(acc[ti][tj][r]);
      }
}

__global__ __launch_bounds__(256) void scan_chunks_r1(
    const short* __restrict__ qb, const short* __restrict__ kb,
    const short* __restrict__ vb, short* __restrict__ yb)
{
  __shared__ __align__(16) short qs[64 * 72];
  __shared__ __align__(16) short ks[64 * 72];
  __shared__ __align__(16) short kT[64 * 72];
  __shared__ __align__(16) short vT[64 * 72];
  __shared__ __align__(16) short Sb[64 * 72];
  __shared__ __align__(16) short Ps[64 * 72];
  const int bh = blockIdx.x;
  const int b = bh >> 4, h = bh & 15;
  const int tid = threadIdx.x;
  const int w = tid >> 6, lane = tid & 63, quad = lane >> 4, l16 = lane & 15;
  const int srow = tid >> 2, sseg = (tid & 3) << 4;
  const size_t base = (size_t)bh * 4096 * 64;
  f4 accS[4];
  #pragma unroll
  for (int i = 0; i < 4; i++) accS[i] = {0.f, 0.f, 0.f, 0.f};
  for (int c = 0; c < 64; c++) {
    __syncthreads();
    {
      size_t g = base + ((size_t)(c * 64 + srow)) * 64 + sseg;
      const float4* qp = reinterpret_cast<const float4*>(qb + g);
      float4 q0 = qp[0], q1 = qp[1];
      *reinterpret_cast<float4*>(&qs[srow * 72 + sseg]) = q0;
      *reinterpret_cast<float4*>(&qs[srow * 72 + sseg + 8]) = q1;
      const float4* kp = reinterpret_cast<const float4*>(kb + g);
      union { float4 v[2]; short s[16]; } ku;
      ku.v[0] = kp[0]; ku.v[1] = kp[1];
      *reinterpret_cast<float4*>(&ks[srow * 72 + sseg]) = ku.v[0];
      *reinterpret_cast<float4*>(&ks[srow * 72 + sseg + 8]) = ku.v[1];
      #pragma unroll
      for (int i = 0; i < 16; i++) kT[(sseg + i) * 72 + srow] = ku.s[i];
      const float4* vp = reinterpret_cast<const float4*>(vb + g);
      union { float4 v[2]; short s[16]; } vu;
      vu.v[0] = vp[0]; vu.v[1] = vp[1];
      #pragma unroll
      for (int i = 0; i < 16; i++) vT[(sseg + i) * 72 + srow] = vu.s[i];
    }
    #pragma unroll
    for (int ti = 0; ti < 4; ti++)
      #pragma unroll
      for (int r = 0; r < 4; r++)
        Sb[(ti * 16 + quad * 4 + r) * 72 + w * 16 + l16] = f2bf(accS[ti][r]);
    __syncthreads();
    s16x8 qa[4][2];
    #pragma unroll
    for (int ti = 0; ti < 4; ti++)
      #pragma unroll
      for (int kh = 0; kh < 2; kh++)
        qa[ti][kh] = *reinterpret_cast<const s16x8*>(&qs[(ti * 16 + l16) * 72 + kh * 32 + quad * 8]);
    s16x8 kf[2];
    #pragma unroll
    for (int kh = 0; kh < 2; kh++)
      kf[kh] = *reinterpret_cast<const s16x8*>(&ks[(w * 16 + l16) * 72 + kh * 32 + quad * 8]);
    #pragma unroll
    for (int ti = 0; ti < 4; ti++) {
      f4 z = {0.f, 0.f, 0.f, 0.f};
      z = __builtin_amdgcn_mfma_f32_16x16x32_bf16(qa[ti][0], kf[0], z, 0, 0, 0);
      z = __builtin_amdgcn_mfma_f32_16x16x32_bf16(qa[ti][1], kf[1], z, 0, 0, 0);
      #pragma unroll
      for (int r = 0; r < 4; r++) {
        int t = ti * 16 + quad * 4 + r;
        int s = w * 16 + l16;
        Ps[t * 72 + s] = (s <= t) ? f2bf(z[r]) : (short)0;
      }
    }
    __syncthreads();
    s16x8 vf[2], sf[2];
    #pragma unroll
    for (int kh = 0; kh < 2; kh++) {
      vf[kh] = *reinterpret_cast<const s16x8*>(&vT[(w * 16 + l16) * 72 + kh * 32 + quad * 8]);
      sf[kh] = *reinterpret_cast<const s16x8*>(&Sb[(w * 16 + l16) * 72 + kh * 32 + quad * 8]);
    }
    #pragma unroll
    for (int ti = 0; ti < 4; ti++) {
      f4 z = {0.f, 0.f, 0.f, 0.f};
      s16x8 p0 = *reinterpret_cast<const s16x8*>(&Ps[(ti * 16 + l16) * 72 + quad * 8]);
      s16x8 p1 = *reinterpret_cast<const s16x8*>(&Ps[(ti * 16 + l16) * 72 + 32 + quad * 8]);
      z = __builtin_amdgcn_mfma_f32_16x16x32_bf16(p0, vf[0], z, 0, 0, 0);
      z = __builtin_amdgcn_mfma_f32_16x16x32_bf16(p1, vf[1], z, 0, 0, 0);
      z = __builtin_amdgcn_mfma_f32_16x16x32_bf16(qa[ti][0], sf[0], z, 0, 0, 0);
      z = __builtin_amdgcn_mfma_f32_16x16x32_bf16(qa[ti][1], sf[1], z, 0, 0, 0);
      #pragma unroll
      for (int r = 0; r < 4; r++) {
        int t = ti * 16 + quad * 4 + r;
        int d = w * 16 + l16;
        yb[(((size_t)b * 4096) + c * 64 + t) * 1024 + h * 64 + d] = f2bf(z[r]);
      }
    }
    s16x8 ku0 = *reinterpret_cast<const s16x8*>(&kT[(w * 16 + l16) * 72 + quad * 8]);
    s16x8 ku1 = *reinterpret_cast<const s16x8*>(&kT[(w * 16 + l16) * 72 + 32 + quad * 8]);
    #pragma unroll
    for (int ti = 0; ti < 4; ti++) {
      s16x8 va0 = *reinterpret_cast<const s16x8*>(&vT[(ti * 16 + l16) * 72 + quad * 8]);
      s16x8 va1 = *reinterpret_cast<const s16x8*>(&vT[(ti * 16 + l16) * 72 + 32 + quad * 8]);
      accS[ti] = __builtin_amdgcn_mfma_f32_16x16x32_bf16(va0, ku0, accS[ti], 0, 0, 0);
      accS[ti] = __builtin_amdgcn_mfma_f32_16x16x32_bf16(va1, ku1, accS[ti], 0, 0, 0);
    }
  }
}

__global__ __launch_bounds__(256) void gemm_out_r1(
    const short* __restrict__ A, const float* __restrict__ B, float* __restrict__ C)
{
  __shared__ __align__(16) short As[128 * 40];
  __shared__ __align__(16) short Bs[128 * 40];
  const int n0 = blockIdx.x * 128;
  const int m0 = blockIdx.y * 128;
  const int tid = threadIdx.x;
  const int w = tid >> 6, lane = tid & 63, quad = lane >> 4, l16 = lane & 15;
  const int wm = (w >> 1) << 6, wn = (w & 1) << 6;
  f4 acc[4][4];
  #pragma unroll
  for (int i = 0; i < 4; i++)
    #pragma unroll
    for (int j = 0; j < 4; j++) acc[i][j] = {0.f, 0.f, 0.f, 0.f};
  const int arow = tid >> 1, aseg = (tid & 1) << 4;
  const int brow = tid >> 3, bseg = (tid & 7) << 4;
  for (int k0 = 0; k0 < 1024; k0 += 32) {
    __syncthreads();
    {
      const float4* ap = reinterpret_cast<const float4*>(A + (size_t)(m0 + arow) * 1024 + k0 + aseg);
      float4 a0 = ap[0], a1 = ap[1];
      float4* dst = reinterpret_cast<float4*>(&As[arow * 40 + aseg]);
      dst[0] = a0; dst[1] = a1;
    }
    {
      const float4* bp = reinterpret_cast<const float4*>(B + (size_t)(k0 + brow) * 1024 + n0 + bseg);
      union { float4 v[4]; float f[16]; } bu;
      bu.v[0] = bp[0]; bu.v[1] = bp[1]; bu.v[2] = bp[2]; bu.v[3] = bp[3];
      #pragma unroll
      for (int i = 0; i < 16; i++) Bs[(bseg + i) * 40 + brow] = f2bf(bu.f[i]);
    }
    __syncthreads();
    s16x8 afr[4], bfr[4];
    #pragma unroll
    for (int t = 0; t < 4; t++)
      afr[t] = *reinterpret_cast<const s16x8*>(&As[(wm + t * 16 + l16) * 40 + quad * 8]);
    #pragma unroll
    for (int t = 0; t < 4; t++)
      bfr[t] = *reinterpret_cast<const s16x8*>(&Bs[(wn + t * 16 + l16) * 40 + quad * 8]);
    #pragma unroll
    for (int ti = 0; ti < 4; ti++)
      #pragma unroll
      for (int tj = 0; tj < 4; tj++)
        acc[ti][tj] = __builtin_amdgcn_mfma_f32_16x16x32_bf16(afr[ti], bfr[tj], acc[ti][tj], 0, 0, 0);
  }
  #pragma unroll
  for (int ti = 0; ti < 4; ti++)
    #pragma unroll
    for (int tj = 0; tj < 4; tj++)
      #pragma unroll
      for (int r = 0; r < 4; r++) {
        int i = m0 + wm + ti * 16 + quad * 4 + r;
        int j = n0 + wn + tj * 16 + l16;
        C[(size_t)i * 1024 + j] = acc[ti][tj][r];
      }
}

extern "C" void kernel_launch(void* const* d_in, const int* in_sizes, int n_in,
                              void* d_out, int out_size, void* d_ws, size_t ws_size,
                              hipStream_t stream) {
  const float* x    = (const float*)d_in[0];   // (4,4096,1024) fp32
  const float* Wqkv = (const float*)d_in[1];   // (1024,3072) fp32
  const float* Wo   = (const float*)d_in[2];   // (1024,1024) fp32
  float* out = (float*)d_out;                  // (4,4096,1024) fp32

  short* qb = (short*)d_ws;                    // 32 MB each region
  short* kb = qb + (size_t)16777216;
  short* vb = kb + (size_t)16777216;
  short* yb = vb + (size_t)16777216;

  const size_t NEED = 176160768;  // 168 MB fast-path footprint
  if (ws_size >= NEED) {
    short* Gs    = yb + (size_t)16777216;      // 32 MB: G then Spre (in-place)
    short* WqkvT = Gs + (size_t)16777216;      // 6 MB
    short* WoT   = WqkvT + (size_t)3145728;    // 2 MB

    transpose_cast<<<dim3(96, 32), 256, 0, stream>>>(Wqkv, WqkvT, 1024, 3072);
    transpose_cast<<<dim3(32, 32), 256, 0, stream>>>(Wo, WoT, 1024, 1024);
    gemm_qkv_v2   <<<dim3(24, 128), 256, 0, stream>>>(x, WqkvT, qb, kb, vb);
    ln_k          <<<dim3(65536),   256, 0, stream>>>(kb);
    chunk_outer   <<<dim3(4096),    256, 0, stream>>>(kb, vb, Gs);
    prefix_S      <<<dim3(256),     256, 0, stream>>>(Gs);
    chunk_out     <<<dim3(4096),    256, 0, stream>>>(qb, kb, vb, Gs, yb);
    gemm_out_v2   <<<dim3(8, 128),  256, 0, stream>>>(yb, WoT, out);
  } else {
    gemm_qkv_r1   <<<dim3(24, 128), 256, 0, stream>>>(x, Wqkv, qb, kb, vb);
    ln_k          <<<dim3(65536),   256, 0, stream>>>(kb);
    scan_chunks_r1<<<dim3(64),      256, 0, stream>>>(qb, kb, vb, yb);
    gemm_out_r1   <<<dim3(8, 128),  256, 0, stream>>>(yb, Wo, out);
  }
}

// Round 3
// 364.448 us; speedup vs baseline: 1.9733x; 1.2833x over previous
//
#include <hip/hip_runtime.h>

#define EPS 1e-5f

typedef __attribute__((ext_vector_type(8))) short s16x8;
typedef __attribute__((ext_vector_type(4))) float f4;

__device__ __forceinline__ short f2bf(float f) {
  union { float f; unsigned u; } x; x.f = f;
  unsigned r = x.u + 0x7fffu + ((x.u >> 16) & 1u);
  return (short)(r >> 16);
}
__device__ __forceinline__ float bf2f(short s) {
  union { unsigned u; float f; } x; x.u = ((unsigned)(unsigned short)s) << 16;
  return x.f;
}
__device__ __forceinline__ void gll16(const short* g, short* l) {
  __builtin_amdgcn_global_load_lds((const __attribute__((address_space(1))) void*)g,
                                   (__attribute__((address_space(3))) void*)l, 16, 0, 0);
}

// ---------------------------------------------------------------------------
// cast_x: fp32 -> bf16, 8 elems/thread, vectorized.
// ---------------------------------------------------------------------------
__global__ __launch_bounds__(256) void cast_x(
    const float* __restrict__ x, short* __restrict__ xb)
{
  const size_t i = ((size_t)blockIdx.x * 256 + threadIdx.x) * 8;
  const float4* p = reinterpret_cast<const float4*>(x + i);
  float4 a = p[0], b = p[1];
  union { uint4 v; short s[8]; } o;
  o.s[0] = f2bf(a.x); o.s[1] = f2bf(a.y); o.s[2] = f2bf(a.z); o.s[3] = f2bf(a.w);
  o.s[4] = f2bf(b.x); o.s[5] = f2bf(b.y); o.s[6] = f2bf(b.z); o.s[7] = f2bf(b.w);
  *reinterpret_cast<uint4*>(xb + i) = o.v;
}

// ---------------------------------------------------------------------------
// Transpose+cast: WT[n][k] (bf16) = W[k][n] (fp32). 32x32 tiles.
// ---------------------------------------------------------------------------
__global__ __launch_bounds__(256) void transpose_cast(
    const float* __restrict__ W, short* __restrict__ WT, int K, int N)
{
  __shared__ float tile[32][33];
  const int n0 = blockIdx.x * 32, k0 = blockIdx.y * 32;
  const int tx = threadIdx.x & 31, ty = threadIdx.x >> 5;
  #pragma unroll
  for (int i = 0; i < 4; i++) {
    int r = ty + i * 8;
    tile[r][tx] = W[(size_t)(k0 + r) * N + n0 + tx];
  }
  __syncthreads();
  #pragma unroll
  for (int i = 0; i < 4; i++) {
    int r = ty + i * 8;
    WT[(size_t)(n0 + r) * K + k0 + tx] = f2bf(tile[tx][r]);
  }
}

// ---------------------------------------------------------------------------
// GEMM1 v3: full m97 structure (both operands via global_load_lds, bf16),
// XCD-ownership swizzle (each XCD owns all 24 n-blocks of its strips),
// LDS-transposed vectorized epilogue scattering q/k/v [BH][L][64].
// ---------------------------------------------------------------------------
__global__ __launch_bounds__(256) void gemm_qkv_v3(
    const short* __restrict__ A, const short* __restrict__ BT,
    short* __restrict__ qb, short* __restrict__ kb, short* __restrict__ vb)
{
  // K-loop: As = lds[0..4096), Bs = lds[4096..8192). Epilogue: 4 x 64x68 stage.
  __shared__ __align__(16) short lds[4 * 64 * 68];
  short* As = lds;
  short* Bs = lds + 4096;

  const int p = blockIdx.x;          // 3072 blocks
  const int slot = p >> 3;
  const int strip = (p & 7) + 8 * (slot / 24);
  const int nb = slot % 24;
  const int m0 = strip * 128, n0 = nb * 128;

  const int tid = threadIdx.x;
  const int w = tid >> 6, lane = tid & 63, quad = lane >> 4, l16 = lane & 15;
  const int wm = (w >> 1) << 6, wn = (w & 1) << 6;

  f4 acc[4][4];
  #pragma unroll
  for (int i = 0; i < 4; i++)
    #pragma unroll
    for (int j = 0; j < 4; j++) acc[i][j] = {0.f, 0.f, 0.f, 0.f};

  const int row = w * 32 + (lane >> 2), ofs = (lane & 3) << 3;

  for (int k0 = 0; k0 < 1024; k0 += 32) {
    __syncthreads();
    gll16(A + (size_t)(m0 + row) * 1024 + k0 + ofs, &As[(w * 32) * 32]);
    gll16(A + (size_t)(m0 + row + 16) * 1024 + k0 + ofs, &As[(w * 32 + 16) * 32]);
    gll16(BT + (size_t)(n0 + row) * 1024 + k0 + ofs, &Bs[(w * 32) * 32]);
    gll16(BT + (size_t)(n0 + row + 16) * 1024 + k0 + ofs, &Bs[(w * 32 + 16) * 32]);
    __syncthreads();
    s16x8 afr[4], bfr[4];
    #pragma unroll
    for (int t = 0; t < 4; t++)
      afr[t] = *reinterpret_cast<const s16x8*>(&As[(wm + t * 16 + l16) * 32 + quad * 8]);
    #pragma unroll
    for (int t = 0; t < 4; t++)
      bfr[t] = *reinterpret_cast<const s16x8*>(&Bs[(wn + t * 16 + l16) * 32 + quad * 8]);
    #pragma unroll
    for (int ti = 0; ti < 4; ti++)
      #pragma unroll
      for (int tj = 0; tj < 4; tj++)
        acc[ti][tj] = __builtin_amdgcn_mfma_f32_16x16x32_bf16(afr[ti], bfr[tj], acc[ti][tj], 0, 0, 0);
  }

  // epilogue: stage wave quadrant (64x64) in LDS, then vectorized head-scatter
  __syncthreads();   // other waves may still read As/Bs region we overwrite
  short* st = &lds[w * 64 * 68];
  #pragma unroll
  for (int ti = 0; ti < 4; ti++)
    #pragma unroll
    for (int tj = 0; tj < 4; tj++)
      #pragma unroll
      for (int r = 0; r < 4; r++)
        st[(ti * 16 + quad * 4 + r) * 68 + tj * 16 + l16] = f2bf(acc[ti][tj][r]);
  // wave-local: LDS writes/reads by same wave; compiler inserts lgkmcnt waits
  const int j0 = n0 + wn;                 // quadrant col base, 64-aligned
  const int sq = j0 >> 10;
  const int hh = (j0 >> 6) & 15;
  short* dbuf = (sq == 0) ? qb : (sq == 1) ? kb : vb;
  const int rr = lane >> 3, c8 = (lane & 7) << 3;
  #pragma unroll
  for (int it = 0; it < 8; it++) {
    int i = m0 + wm + it * 8 + rr;
    int bb = i >> 12, ll = i & 4095;
    uint4 val = *reinterpret_cast<const uint4*>(&st[(it * 8 + rr) * 68 + c8]);
    *reinterpret_cast<uint4*>(&dbuf[(((size_t)(bb * 16 + hh)) * 4096 + ll) * 64 + c8]) = val;
  }
}

// ---------------------------------------------------------------------------
// LayerNorm kernel (fallback path only; fast path fuses LN).
// ---------------------------------------------------------------------------
__global__ __launch_bounds__(256) void ln_k(short* __restrict__ kbuf)
{
  const int row = blockIdx.x * 4 + (threadIdx.x >> 6);
  const int lane = threadIdx.x & 63;
  const size_t idx = (size_t)row * 64 + lane;
  float v = bf2f(kbuf[idx]);
  float s = v, s2 = v * v;
  #pragma unroll
  for (int off = 32; off; off >>= 1) {
    s += __shfl_xor(s, off);
    s2 += __shfl_xor(s2, off);
  }
  float mean = s * (1.f / 64.f);
  float var = s2 * (1.f / 64.f) - mean * mean;
  float rstd = rsqrtf(var + EPS);
  kbuf[idx] = f2bf((v - mean) * rstd);
}

// ---------------------------------------------------------------------------
// Scan pass A: G[bh][c] = sum_t v[t,:] k_ln[t,:]^T with LN(k) fused.
// One block per (bh,c).
// ---------------------------------------------------------------------------
__global__ __launch_bounds__(256) void chunk_outer(
    const short* __restrict__ kb, const short* __restrict__ vb,
    short* __restrict__ G)
{
  __shared__ __align__(16) short kT[64 * 72];
  __shared__ __align__(16) short vT[64 * 72];
  const int bh = blockIdx.x >> 6, c = blockIdx.x & 63;
  const int tid = threadIdx.x;
  const int w = tid >> 6, lane = tid & 63, quad = lane >> 4, l16 = lane & 15;
  const int srow = tid >> 2, sseg = (tid & 3) << 4;
  const size_t base = (size_t)bh * 262144 + (size_t)(c * 64 + srow) * 64 + sseg;

  {
    const float4* kp = reinterpret_cast<const float4*>(kb + base);
    union { float4 v[2]; short s[16]; } ku;
    ku.v[0] = kp[0]; ku.v[1] = kp[1];
    // fused LN over the 64-elem row (4 lanes x 16 elems, lanes tid&3)
    float kv[16]; float s = 0.f, s2 = 0.f;
    #pragma unroll
    for (int i = 0; i < 16; i++) { kv[i] = bf2f(ku.s[i]); s += kv[i]; s2 += kv[i] * kv[i]; }
    s += __shfl_xor(s, 1);  s2 += __shfl_xor(s2, 1);
    s += __shfl_xor(s, 2);  s2 += __shfl_xor(s2, 2);
    float mean = s * (1.f / 64.f);
    float var = s2 * (1.f / 64.f) - mean * mean;
    float rstd = rsqrtf(var + EPS);
    #pragma unroll
    for (int i = 0; i < 16; i++) kT[(sseg + i) * 72 + srow] = f2bf((kv[i] - mean) * rstd);
    const float4* vp = reinterpret_cast<const float4*>(vb + base);
    union { float4 v[2]; short s[16]; } vu;
    vu.v[0] = vp[0]; vu.v[1] = vp[1];
    #pragma unroll
    for (int i = 0; i < 16; i++) vT[(sseg + i) * 72 + srow] = vu.s[i];
  }
  __syncthreads();
  s16x8 va0 = *reinterpret_cast<const s16x8*>(&vT[(w * 16 + l16) * 72 + quad * 8]);
  s16x8 va1 = *reinterpret_cast<const s16x8*>(&vT[(w * 16 + l16) * 72 + 32 + quad * 8]);
  short* Gc = G + ((size_t)blockIdx.x) * 4096;
  #pragma unroll
  for (int tj = 0; tj < 4; tj++) {
    s16x8 kb0 = *reinterpret_cast<const s16x8*>(&kT[(tj * 16 + l16) * 72 + quad * 8]);
    s16x8 kb1 = *reinterpret_cast<const s16x8*>(&kT[(tj * 16 + l16) * 72 + 32 + quad * 8]);
    f4 z = {0.f, 0.f, 0.f, 0.f};
    z = __builtin_amdgcn_mfma_f32_16x16x32_bf16(va0, kb0, z, 0, 0, 0);
    z = __builtin_amdgcn_mfma_f32_16x16x32_bf16(va1, kb1, z, 0, 0, 0);
    #pragma unroll
    for (int r = 0; r < 4; r++)
      Gc[(w * 16 + quad * 4 + r) * 64 + tj * 16 + l16] = f2bf(z[r]);
  }
}

// ---------------------------------------------------------------------------
// Scan pass B: in-place exclusive prefix over c.
// ---------------------------------------------------------------------------
__global__ __launch_bounds__(256) void prefix_S(short* __restrict__ G)
{
  const int bh = blockIdx.x >> 2, rg = blockIdx.x & 3;
  const size_t base = (size_t)bh * 262144 + rg * 1024 + threadIdx.x * 4;
  float s0 = 0.f, s1 = 0.f, s2 = 0.f, s3 = 0.f;
  for (int c = 0; c < 64; c++) {
    short* p = G + base + (size_t)c * 4096;
    union { uint2 v; short s[4]; } gu;
    gu.v = *reinterpret_cast<const uint2*>(p);
    float g0 = bf2f(gu.s[0]), g1 = bf2f(gu.s[1]), g2 = bf2f(gu.s[2]), g3 = bf2f(gu.s[3]);
    union { uint2 v; short s[4]; } su;
    su.s[0] = f2bf(s0); su.s[1] = f2bf(s1); su.s[2] = f2bf(s2); su.s[3] = f2bf(s3);
    *reinterpret_cast<uint2*>(p) = su.v;
    s0 += g0; s1 += g1; s2 += g2; s3 += g3;
  }
}

// ---------------------------------------------------------------------------
// Scan pass C: y = tril(q k_ln^T) v + q S^T-contract, LN(k) fused in-reg.
// ---------------------------------------------------------------------------
__global__ __launch_bounds__(256) void chunk_out(
    const short* __restrict__ qb, const short* __restrict__ kb,
    const short* __restrict__ vb, const short* __restrict__ S,
    short* __restrict__ yb)
{
  __shared__ __align__(16) short vT[64 * 72];
  __shared__ __align__(16) short Ps[64 * 72];
  const int bh = blockIdx.x >> 6, c = blockIdx.x & 63;
  const int b = bh >> 4, h = bh & 15;
  const int tid = threadIdx.x;
  const int w = tid >> 6, lane = tid & 63, quad = lane >> 4, l16 = lane & 15;
  const int srow = tid >> 2, sseg = (tid & 3) << 4;
  const size_t base = (size_t)bh * 262144 + (size_t)c * 4096;

  {
    const float4* vp = reinterpret_cast<const float4*>(vb + base + (size_t)srow * 64 + sseg);
    union { float4 v[2]; short s[16]; } vu;
    vu.v[0] = vp[0]; vu.v[1] = vp[1];
    #pragma unroll
    for (int i = 0; i < 16; i++) vT[(sseg + i) * 72 + srow] = vu.s[i];
  }
  s16x8 qa[4][2], kf[2], sf[2];
  #pragma unroll
  for (int ti = 0; ti < 4; ti++)
    #pragma unroll
    for (int kh = 0; kh < 2; kh++)
      qa[ti][kh] = *reinterpret_cast<const s16x8*>(
          qb + base + (size_t)(ti * 16 + l16) * 64 + kh * 32 + quad * 8);
  #pragma unroll
  for (int kh = 0; kh < 2; kh++) {
    kf[kh] = *reinterpret_cast<const s16x8*>(
        kb + base + (size_t)(w * 16 + l16) * 64 + kh * 32 + quad * 8);
    sf[kh] = *reinterpret_cast<const s16x8*>(
        S + base + (size_t)(w * 16 + l16) * 64 + kh * 32 + quad * 8);
  }
  { // fused LN of k row (w*16+l16): row spread across lanes ^16, ^32 (quads)
    float kv[16]; float s = 0.f, s2 = 0.f;
    #pragma unroll
    for (int kh = 0; kh < 2; kh++)
      #pragma unroll
      for (int i = 0; i < 8; i++) {
        float f = bf2f(kf[kh][i]); kv[kh * 8 + i] = f; s += f; s2 += f * f;
      }
    s += __shfl_xor(s, 16);  s2 += __shfl_xor(s2, 16);
    s += __shfl_xor(s, 32);  s2 += __shfl_xor(s2, 32);
    float mean = s * (1.f / 64.f);
    float var = s2 * (1.f / 64.f) - mean * mean;
    float rstd = rsqrtf(var + EPS);
    #pragma unroll
    for (int kh = 0; kh < 2; kh++)
      #pragma unroll
      for (int i = 0; i < 8; i++)
        kf[kh][i] = f2bf((kv[kh * 8 + i] - mean) * rstd);
  }
  __syncthreads();
  #pragma unroll
  for (int ti = 0; ti < 4; ti++) {
    f4 z = {0.f, 0.f, 0.f, 0.f};
    z = __builtin_amdgcn_mfma_f32_16x16x32_bf16(qa[ti][0], kf[0], z, 0, 0, 0);
    z = __builtin_amdgcn_mfma_f32_16x16x32_bf16(qa[ti][1], kf[1], z, 0, 0, 0);
    #pragma unroll
    for (int r = 0; r < 4; r++) {
      int t = ti * 16 + quad * 4 + r;
      int s = w * 16 + l16;
      Ps[t * 72 + s] = (s <= t) ? f2bf(z[r]) : (short)0;
    }
  }
  __syncthreads();
  s16x8 vf0 = *reinterpret_cast<const s16x8*>(&vT[(w * 16 + l16) * 72 + quad * 8]);
  s16x8 vf1 = *reinterpret_cast<const s16x8*>(&vT[(w * 16 + l16) * 72 + 32 + quad * 8]);
  #pragma unroll
  for (int ti = 0; ti < 4; ti++) {
    f4 z = {0.f, 0.f, 0.f, 0.f};
    s16x8 p0 = *reinterpret_cast<const s16x8*>(&Ps[(ti * 16 + l16) * 72 + quad * 8]);
    s16x8 p1 = *reinterpret_cast<const s16x8*>(&Ps[(ti * 16 + l16) * 72 + 32 + quad * 8]);
    z = __builtin_amdgcn_mfma_f32_16x16x32_bf16(p0, vf0, z, 0, 0, 0);
    z = __builtin_amdgcn_mfma_f32_16x16x32_bf16(p1, vf1, z, 0, 0, 0);
    z = __builtin_amdgcn_mfma_f32_16x16x32_bf16(qa[ti][0], sf[0], z, 0, 0, 0);
    z = __builtin_amdgcn_mfma_f32_16x16x32_bf16(qa[ti][1], sf[1], z, 0, 0, 0);
    #pragma unroll
    for (int r = 0; r < 4; r++) {
      int t = ti * 16 + quad * 4 + r;
      int d = w * 16 + l16;
      yb[(((size_t)b * 4096) + c * 64 + t) * 1024 + h * 64 + d] = f2bf(z[r]);
    }
  }
}

// ---------------------------------------------------------------------------
// GEMM2 v3: out = y(bf16) @ WoT^T, m97 structure + XCD swizzle (8 nb/strip).
// ---------------------------------------------------------------------------
__global__ __launch_bounds__(256) void gemm_out_v3(
    const short* __restrict__ A, const short* __restrict__ BT, float* __restrict__ C)
{
  __shared__ __align__(16) short As[128 * 32];
  __shared__ __align__(16) short Bs[128 * 32];
  const int p = blockIdx.x;          // 1024 blocks
  const int slot = p >> 3;
  const int strip = (p & 7) + 8 * (slot >> 3);
  const int nb = slot & 7;
  const int m0 = strip * 128, n0 = nb * 128;
  const int tid = threadIdx.x;
  const int w = tid >> 6, lane = tid & 63, quad = lane >> 4, l16 = lane & 15;
  const int wm = (w >> 1) << 6, wn = (w & 1) << 6;

  f4 acc[4][4];
  #pragma unroll
  for (int i = 0; i < 4; i++)
    #pragma unroll
    for (int j = 0; j < 4; j++) acc[i][j] = {0.f, 0.f, 0.f, 0.f};

  const int row = w * 32 + (lane >> 2), ofs = (lane & 3) << 3;

  for (int k0 = 0; k0 < 1024; k0 += 32) {
    __syncthreads();
    gll16(A + (size_t)(m0 + row) * 1024 + k0 + ofs, &As[(w * 32) * 32]);
    gll16(A + (size_t)(m0 + row + 16) * 1024 + k0 + ofs, &As[(w * 32 + 16) * 32]);
    gll16(BT + (size_t)(n0 + row) * 1024 + k0 + ofs, &Bs[(w * 32) * 32]);
    gll16(BT + (size_t)(n0 + row + 16) * 1024 + k0 + ofs, &Bs[(w * 32 + 16) * 32]);
    __syncthreads();
    s16x8 afr[4], bfr[4];
    #pragma unroll
    for (int t = 0; t < 4; t++)
      afr[t] = *reinterpret_cast<const s16x8*>(&As[(wm + t * 16 + l16) * 32 + quad * 8]);
    #pragma unroll
    for (int t = 0; t < 4; t++)
      bfr[t] = *reinterpret_cast<const s16x8*>(&Bs[(wn + t * 16 + l16) * 32 + quad * 8]);
    #pragma unroll
    for (int ti = 0; ti < 4; ti++)
      #pragma unroll
      for (int tj = 0; tj < 4; tj++)
        acc[ti][tj] = __builtin_amdgcn_mfma_f32_16x16x32_bf16(afr[ti], bfr[tj], acc[ti][tj], 0, 0, 0);
  }
  #pragma unroll
  for (int ti = 0; ti < 4; ti++)
    #pragma unroll
    for (int tj = 0; tj < 4; tj++)
      #pragma unroll
      for (int r = 0; r < 4; r++) {
        int i = m0 + wm + ti * 16 + quad * 4 + r;
        int j = n0 + wn + tj * 16 + l16;
        C[(size_t)i * 1024 + j] = acc[ti][tj][r];
      }
}

// ===========================================================================
// Fallback path (round-1 kernels) for small ws.
// ===========================================================================
__global__ __launch_bounds__(256) void gemm_qkv_r1(
    const float* __restrict__ A, const float* __restrict__ B,
    short* __restrict__ qb, short* __restrict__ kb, short* __restrict__ vb)
{
  __shared__ __align__(16) short As[128 * 40];
  __shared__ __align__(16) short Bs[128 * 40];
  const int n0 = blockIdx.x * 128;
  const int m0 = blockIdx.y * 128;
  const int tid = threadIdx.x;
  const int w = tid >> 6, lane = tid & 63, quad = lane >> 4, l16 = lane & 15;
  const int wm = (w >> 1) << 6, wn = (w & 1) << 6;
  f4 acc[4][4];
  #pragma unroll
  for (int i = 0; i < 4; i++)
    #pragma unroll
    for (int j = 0; j < 4; j++) acc[i][j] = {0.f, 0.f, 0.f, 0.f};
  const int arow = tid >> 1, aseg = (tid & 1) << 4;
  const int brow = tid >> 3, bseg = (tid & 7) << 4;
  for (int k0 = 0; k0 < 1024; k0 += 32) {
    __syncthreads();
    {
      const float4* ap = reinterpret_cast<const float4*>(A + (size_t)(m0 + arow) * 1024 + k0 + aseg);
      union { float4 v[4]; float f[16]; } af;
      af.v[0] = ap[0]; af.v[1] = ap[1]; af.v[2] = ap[2]; af.v[3] = ap[3];
      union { float4 v[2]; short s[16]; } ao;
      #pragma unroll
      for (int i = 0; i < 16; i++) ao.s[i] = f2bf(af.f[i]);
      float4* dst = reinterpret_cast<float4*>(&As[arow * 40 + aseg]);
      dst[0] = ao.v[0]; dst[1] = ao.v[1];
    }
    {
      const float4* bp = reinterpret_cast<const float4*>(B + (size_t)(k0 + brow) * 3072 + n0 + bseg);
      union { float4 v[4]; float f[16]; } bu;
      bu.v[0] = bp[0]; bu.v[1] = bp[1]; bu.v[2] = bp[2]; bu.v[3] = bp[3];
      #pragma unroll
      for (int i = 0; i < 16; i++) Bs[(bseg + i) * 40 + brow] = f2bf(bu.f[i]);
    }
    __syncthreads();
    s16x8 afr[4], bfr[4];
    #pragma unroll
    for (int t = 0; t < 4; t++)
      afr[t] = *reinterpret_cast<const s16x8*>(&As[(wm + t * 16 + l16) * 40 + quad * 8]);
    #pragma unroll
    for (int t = 0; t < 4; t++)
      bfr[t] = *reinterpret_cast<const s16x8*>(&Bs[(wn + t * 16 + l16) * 40 + quad * 8]);
    #pragma unroll
    for (int ti = 0; ti < 4; ti++)
      #pragma unroll
      for (int tj = 0; tj < 4; tj++)
        acc[ti][tj] = __builtin_amdgcn_mfma_f32_16x16x32_bf16(afr[ti], bfr[tj], acc[ti][tj], 0, 0, 0);
  }
  const int sq = n0 >> 10;
  short* dbuf = (sq == 0) ? qb : (sq == 1) ? kb : vb;
  #pragma unroll
  for (int ti = 0; ti < 4; ti++)
    #pragma unroll
    for (int tj = 0; tj < 4; tj++)
      #pragma unroll
      for (int r = 0; r < 4; r++) {
        int i = m0 + wm + ti * 16 + quad * 4 + r;
        int j = n0 + wn + tj * 16 + l16;
        int hh = (j >> 6) & 15, dd = j & 63;
        int bb = i >> 12, ll = i & 4095;
        dbuf[(((size_t)(bb * 16 + hh)) * 4096 + ll) * 64 + dd] = f2bf(acc[ti][tj][r]);
      }
}

__global__ __launch_bounds__(256) void scan_chunks_r1(
    const short* __restrict__ qb, const short* __restrict__ kb,
    const short* __restrict__ vb, short* __restrict__ yb)
{
  __shared__ __align__(16) short qs[64 * 72];
  __shared__ __align__(16) short ks[64 * 72];
  __shared__ __align__(16) short kT[64 * 72];
  __shared__ __align__(16) short vT[64 * 72];
  __shared__ __align__(16) short Sb[64 * 72];
  __shared__ __align__(16) short Ps[64 * 72];
  const int bh = blockIdx.x;
  const int b = bh >> 4, h = bh & 15;
  const int tid = threadIdx.x;
  const int w = tid >> 6, lane = tid & 63, quad = lane >> 4, l16 = lane & 15;
  const int srow = tid >> 2, sseg = (tid & 3) << 4;
  const size_t base = (size_t)bh * 4096 * 64;
  f4 accS[4];
  #pragma unroll
  for (int i = 0; i < 4; i++) accS[i] = {0.f, 0.f, 0.f, 0.f};
  for (int c = 0; c < 64; c++) {
    __syncthreads();
    {
      size_t g = base + ((size_t)(c * 64 + srow)) * 64 + sseg;
      const float4* qp = reinterpret_cast<const float4*>(qb + g);
      float4 q0 = qp[0], q1 = qp[1];
      *reinterpret_cast<float4*>(&qs[srow * 72 + sseg]) = q0;
      *reinterpret_cast<float4*>(&qs[srow * 72 + sseg + 8]) = q1;
      const float4* kp = reinterpret_cast<const float4*>(kb + g);
      union { float4 v[2]; short s[16]; } ku;
      ku.v[0] = kp[0]; ku.v[1] = kp[1];
      *reinterpret_cast<float4*>(&ks[srow * 72 + sseg]) = ku.v[0];
      *reinterpret_cast<float4*>(&ks[srow * 72 + sseg + 8]) = ku.v[1];
      #pragma unroll
      for (int i = 0; i < 16; i++) kT[(sseg + i) * 72 + srow] = ku.s[i];
      const float4* vp = reinterpret_cast<const float4*>(vb + g);
      union { float4 v[2]; short s[16]; } vu;
      vu.v[0] = vp[0]; vu.v[1] = vp[1];
      #pragma unroll
      for (int i = 0; i < 16; i++) vT[(sseg + i) * 72 + srow] = vu.s[i];
    }
    #pragma unroll
    for (int ti = 0; ti < 4; ti++)
      #pragma unroll
      for (int r = 0; r < 4; r++)
        Sb[(ti * 16 + quad * 4 + r) * 72 + w * 16 + l16] = f2bf(accS[ti][r]);
    __syncthreads();
    s16x8 qa[4][2];
    #pragma unroll
    for (int ti = 0; ti < 4; ti++)
      #pragma unroll
      for (int kh = 0; kh < 2; kh++)
        qa[ti][kh] = *reinterpret_cast<const s16x8*>(&qs[(ti * 16 + l16) * 72 + kh * 32 + quad * 8]);
    s16x8 kf[2];
    #pragma unroll
    for (int kh = 0; kh < 2; kh++)
      kf[kh] = *reinterpret_cast<const s16x8*>(&ks[(w * 16 + l16) * 72 + kh * 32 + quad * 8]);
    #pragma unroll
    for (int ti = 0; ti < 4; ti++) {
      f4 z = {0.f, 0.f, 0.f, 0.f};
      z = __builtin_amdgcn_mfma_f32_16x16x32_bf16(qa[ti][0], kf[0], z, 0, 0, 0);
      z = __builtin_amdgcn_mfma_f32_16x16x32_bf16(qa[ti][1], kf[1], z, 0, 0, 0);
      #pragma unroll
      for (int r = 0; r < 4; r++) {
        int t = ti * 16 + quad * 4 + r;
        int s = w * 16 + l16;
        Ps[t * 72 + s] = (s <= t) ? f2bf(z[r]) : (short)0;
      }
    }
    __syncthreads();
    s16x8 vf[2], sf[2];
    #pragma unroll
    for (int kh = 0; kh < 2; kh++) {
      vf[kh] = *reinterpret_cast<const s16x8*>(&vT[(w * 16 + l16) * 72 + kh * 32 + quad * 8]);
      sf[kh] = *reinterpret_cast<const s16x8*>(&Sb[(w * 16 + l16) * 72 + kh * 32 + quad * 8]);
    }
    #pragma unroll
    for (int ti = 0; ti < 4; ti++) {
      f4 z = {0.f, 0.f, 0.f, 0.f};
      s16x8 p0 = *reinterpret_cast<const s16x8*>(&Ps[(ti * 16 + l16) * 72 + quad * 8]);
      s16x8 p1 = *reinterpret_cast<const s16x8*>(&Ps[(ti * 16 + l16) * 72 + 32 + quad * 8]);
      z = __builtin_amdgcn_mfma_f32_16x16x32_bf16(p0, vf[0], z, 0, 0, 0);
      z = __builtin_amdgcn_mfma_f32_16x16x32_bf16(p1, vf[1], z, 0, 0, 0);
      z = __builtin_amdgcn_mfma_f32_16x16x32_bf16(qa[ti][0], sf[0], z, 0, 0, 0);
      z = __builtin_amdgcn_mfma_f32_16x16x32_bf16(qa[ti][1], sf[1], z, 0, 0, 0);
      #pragma unroll
      for (int r = 0; r < 4; r++) {
        int t = ti * 16 + quad * 4 + r;
        int d = w * 16 + l16;
        yb[(((size_t)b * 4096) + c * 64 + t) * 1024 + h * 64 + d] = f2bf(z[r]);
      }
    }
    s16x8 ku0 = *reinterpret_cast<const s16x8*>(&kT[(w * 16 + l16) * 72 + quad * 8]);
    s16x8 ku1 = *reinterpret_cast<const s16x8*>(&kT[(w * 16 + l16) * 72 + 32 + quad * 8]);
    #pragma unroll
    for (int ti = 0; ti < 4; ti++) {
      s16x8 va0 = *reinterpret_cast<const s16x8*>(&vT[(ti * 16 + l16) * 72 + quad * 8]);
      s16x8 va1 = *reinterpret_cast<const s16x8*>(&vT[(ti * 16 + l16) * 72 + 32 + quad * 8]);
      accS[ti] = __builtin_amdgcn_mfma_f32_16x16x32_bf16(va0, ku0, accS[ti], 0, 0, 0);
      accS[ti] = __builtin_amdgcn_mfma_f32_16x16x32_bf16(va1, ku1, accS[ti], 0, 0, 0);
    }
  }
}

__global__ __launch_bounds__(256) void gemm_out_r1(
    const short* __restrict__ A, const float* __restrict__ B, float* __restrict__ C)
{
  __shared__ __align__(16) short As[128 * 40];
  __shared__ __align__(16) short Bs[128 * 40];
  const int n0 = blockIdx.x * 128;
  const int m0 = blockIdx.y * 128;
  const int tid = threadIdx.x;
  const int w = tid >> 6, lane = tid & 63, quad = lane >> 4, l16 = lane & 15;
  const int wm = (w >> 1) << 6, wn = (w & 1) << 6;
  f4 acc[4][4];
  #pragma unroll
  for (int i = 0; i < 4; i++)
    #pragma unroll
    for (int j = 0; j < 4; j++) acc[i][j] = {0.f, 0.f, 0.f, 0.f};
  const int arow = tid >> 1, aseg = (tid & 1) << 4;
  const int brow = tid >> 3, bseg = (tid & 7) << 4;
  for (int k0 = 0; k0 < 1024; k0 += 32) {
    __syncthreads();
    {
      const float4* ap = reinterpret_cast<const float4*>(A + (size_t)(m0 + arow) * 1024 + k0 + aseg);
      float4 a0 = ap[0], a1 = ap[1];
      float4* dst = reinterpret_cast<float4*>(&As[arow * 40 + aseg]);
      dst[0] = a0; dst[1] = a1;
    }
    {
      const float4* bp = reinterpret_cast<const float4*>(B + (size_t)(k0 + brow) * 1024 + n0 + bseg);
      union { float4 v[4]; float f[16]; } bu;
      bu.v[0] = bp[0]; bu.v[1] = bp[1]; bu.v[2] = bp[2]; bu.v[3] = bp[3];
      #pragma unroll
      for (int i = 0; i < 16; i++) Bs[(bseg + i) * 40 + brow] = f2bf(bu.f[i]);
    }
    __syncthreads();
    s16x8 afr[4], bfr[4];
    #pragma unroll
    for (int t = 0; t < 4; t++)
      afr[t] = *reinterpret_cast<const s16x8*>(&As[(wm + t * 16 + l16) * 40 + quad * 8]);
    #pragma unroll
    for (int t = 0; t < 4; t++)
      bfr[t] = *reinterpret_cast<const s16x8*>(&Bs[(wn + t * 16 + l16) * 40 + quad * 8]);
    #pragma unroll
    for (int ti = 0; ti < 4; ti++)
      #pragma unroll
      for (int tj = 0; tj < 4; tj++)
        acc[ti][tj] = __builtin_amdgcn_mfma_f32_16x16x32_bf16(afr[ti], bfr[tj], acc[ti][tj], 0, 0, 0);
  }
  #pragma unroll
  for (int ti = 0; ti < 4; ti++)
    #pragma unroll
    for (int tj = 0; tj < 4; tj++)
      #pragma unroll
      for (int r = 0; r < 4; r++) {
        int i = m0 + wm + ti * 16 + quad * 4 + r;
        int j = n0 + wn + tj * 16 + l16;
        C[(size_t)i * 1024 + j] = acc[ti][tj][r];
      }
}

extern "C" void kernel_launch(void* const* d_in, const int* in_sizes, int n_in,
                              void* d_out, int out_size, void* d_ws, size_t ws_size,
                              hipStream_t stream) {
  const float* x    = (const float*)d_in[0];   // (4,4096,1024) fp32
  const float* Wqkv = (const float*)d_in[1];   // (1024,3072) fp32
  const float* Wo   = (const float*)d_in[2];   // (1024,1024) fp32
  float* out = (float*)d_out;                  // (4,4096,1024) fp32

  short* qb = (short*)d_ws;                    // 32 MB each region
  short* kb = qb + (size_t)16777216;
  short* vb = kb + (size_t)16777216;
  short* yb = vb + (size_t)16777216;

  const size_t NEED = 176160768;  // 168 MB fast-path footprint
  if (ws_size >= NEED) {
    short* Gs    = yb + (size_t)16777216;      // 32 MB: xb, then G/S (in-place)
    short* WqkvT = Gs + (size_t)16777216;      // 6 MB
    short* WoT   = WqkvT + (size_t)3145728;    // 2 MB
    short* xb    = Gs;                          // overlay: dead before chunk_outer

    cast_x        <<<dim3(8192),    256, 0, stream>>>(x, xb);
    transpose_cast<<<dim3(96, 32),  256, 0, stream>>>(Wqkv, WqkvT, 1024, 3072);
    transpose_cast<<<dim3(32, 32),  256, 0, stream>>>(Wo, WoT, 1024, 1024);
    gemm_qkv_v3   <<<dim3(3072),    256, 0, stream>>>(xb, WqkvT, qb, kb, vb);
    chunk_outer   <<<dim3(4096),    256, 0, stream>>>(kb, vb, Gs);
    prefix_S      <<<dim3(256),     256, 0, stream>>>(Gs);
    chunk_out     <<<dim3(4096),    256, 0, stream>>>(qb, kb, vb, Gs, yb);
    gemm_out_v3   <<<dim3(1024),    256, 0, stream>>>(yb, WoT, out);
  } else {
    gemm_qkv_r1   <<<dim3(24, 128), 256, 0, stream>>>(x, Wqkv, qb, kb, vb);
    ln_k          <<<dim3(65536),   256, 0, stream>>>(kb);
    scan_chunks_r1<<<dim3(64),      256, 0, stream>>>(qb, kb, vb, yb);
    gemm_out_r1   <<<dim3(8, 128),  256, 0, stream>>>(yb, Wo, out);
  }
}

// Round 4
// 356.578 us; speedup vs baseline: 2.0168x; 1.0221x over previous
//
#include <hip/hip_runtime.h>

#define EPS 1e-5f

typedef __attribute__((ext_vector_type(8))) short s16x8;
typedef __attribute__((ext_vector_type(4))) float f4;

__device__ __forceinline__ short f2bf(float f) {
  union { float f; unsigned u; } x; x.f = f;
  unsigned r = x.u + 0x7fffu + ((x.u >> 16) & 1u);
  return (short)(r >> 16);
}
__device__ __forceinline__ float bf2f(short s) {
  union { unsigned u; float f; } x; x.u = ((unsigned)(unsigned short)s) << 16;
  return x.f;
}
__device__ __forceinline__ void gll16(const short* g, short* l) {
  __builtin_amdgcn_global_load_lds((const __attribute__((address_space(1))) void*)g,
                                   (__attribute__((address_space(3))) void*)l, 16, 0, 0);
}

// ---------------------------------------------------------------------------
// prep: fused  x fp32->bf16 cast  +  Wqkv transpose-cast  +  Wo transpose-cast.
// Grid partition: [0,8192) cast_x; [8192,11264) Wqkv^T; [11264,12288) Wo^T.
// ---------------------------------------------------------------------------
__global__ __launch_bounds__(256) void prep(
    const float* __restrict__ x, const float* __restrict__ Wqkv,
    const float* __restrict__ Wo,
    short* __restrict__ xb, short* __restrict__ WqkvT, short* __restrict__ WoT)
{
  __shared__ float tile[32][33];
  const int bid = blockIdx.x;
  if (bid < 8192) {
    const size_t i = ((size_t)bid * 256 + threadIdx.x) * 8;
    const float4* p = reinterpret_cast<const float4*>(x + i);
    float4 a = p[0], b = p[1];
    union { uint4 v; short s[8]; } o;
    o.s[0] = f2bf(a.x); o.s[1] = f2bf(a.y); o.s[2] = f2bf(a.z); o.s[3] = f2bf(a.w);
    o.s[4] = f2bf(b.x); o.s[5] = f2bf(b.y); o.s[6] = f2bf(b.z); o.s[7] = f2bf(b.w);
    *reinterpret_cast<uint4*>(xb + i) = o.v;
    return;
  }
  const float* W; short* WT; int K, N, t;
  if (bid < 11264) { W = Wqkv; WT = WqkvT; K = 1024; N = 3072; t = bid - 8192;  }
  else             { W = Wo;   WT = WoT;   K = 1024; N = 1024; t = bid - 11264; }
  const int nblk = N >> 5;
  const int n0 = (t % nblk) * 32, k0 = (t / nblk) * 32;
  const int tx = threadIdx.x & 31, ty = threadIdx.x >> 5;
  #pragma unroll
  for (int i = 0; i < 4; i++) {
    int r = ty + i * 8;
    tile[r][tx] = W[(size_t)(k0 + r) * N + n0 + tx];
  }
  __syncthreads();
  #pragma unroll
  for (int i = 0; i < 4; i++) {
    int r = ty + i * 8;
    WT[(size_t)(n0 + r) * K + k0 + tx] = f2bf(tile[tx][r]);
  }
}

// ---------------------------------------------------------------------------
// GEMM1 v4: m97 structure, XCD-ownership swizzle, slim epilogue.
// LDS = 16 KB (K-loop As/Bs only; epilogue stages 16 rows/wave per round
// overlaid on the same buffer) -> ~2x occupancy vs v3's 34.8 KB.
// ---------------------------------------------------------------------------
__global__ __launch_bounds__(256) void gemm_qkv_v4(
    const short* __restrict__ A, const short* __restrict__ BT,
    short* __restrict__ qb, short* __restrict__ kb, short* __restrict__ vb)
{
  __shared__ __align__(16) short lds[8192];   // As [0,4096), Bs [4096,8192)
  short* As = lds;
  short* Bs = lds + 4096;

  const int p = blockIdx.x;          // 3072 blocks
  const int slot = p >> 3;
  const int strip = (p & 7) + 8 * (slot / 24);
  const int nb = slot % 24;
  const int m0 = strip * 128, n0 = nb * 128;

  const int tid = threadIdx.x;
  const int w = tid >> 6, lane = tid & 63, quad = lane >> 4, l16 = lane & 15;
  const int wm = (w >> 1) << 6, wn = (w & 1) << 6;

  f4 acc[4][4];
  #pragma unroll
  for (int i = 0; i < 4; i++)
    #pragma unroll
    for (int j = 0; j < 4; j++) acc[i][j] = {0.f, 0.f, 0.f, 0.f};

  const int row = w * 32 + (lane >> 2), ofs = (lane & 3) << 3;

  for (int k0 = 0; k0 < 1024; k0 += 32) {
    __syncthreads();
    gll16(A + (size_t)(m0 + row) * 1024 + k0 + ofs, &As[(w * 32) * 32]);
    gll16(A + (size_t)(m0 + row + 16) * 1024 + k0 + ofs, &As[(w * 32 + 16) * 32]);
    gll16(BT + (size_t)(n0 + row) * 1024 + k0 + ofs, &Bs[(w * 32) * 32]);
    gll16(BT + (size_t)(n0 + row + 16) * 1024 + k0 + ofs, &Bs[(w * 32 + 16) * 32]);
    __syncthreads();
    s16x8 afr[4], bfr[4];
    #pragma unroll
    for (int t = 0; t < 4; t++)
      afr[t] = *reinterpret_cast<const s16x8*>(&As[(wm + t * 16 + l16) * 32 + quad * 8]);
    #pragma unroll
    for (int t = 0; t < 4; t++)
      bfr[t] = *reinterpret_cast<const s16x8*>(&Bs[(wn + t * 16 + l16) * 32 + quad * 8]);
    #pragma unroll
    for (int ti = 0; ti < 4; ti++)
      #pragma unroll
      for (int tj = 0; tj < 4; tj++)
        acc[ti][tj] = __builtin_amdgcn_mfma_f32_16x16x32_bf16(afr[ti], bfr[tj], acc[ti][tj], 0, 0, 0);
  }

  // slim epilogue: per ti-round stage 16x64 (stride 72) per wave, store uint4.
  __syncthreads();                       // waves may still read As/Bs
  short* st = &lds[w * 16 * 72];         // 4 waves x 1152 shorts < 8192
  const int j0 = n0 + wn;
  const int sq = j0 >> 10;
  const int hh = (j0 >> 6) & 15;
  short* dbuf = (sq == 0) ? qb : (sq == 1) ? kb : vb;
  const int r2 = lane >> 3, c8 = (lane & 7) << 3;
  #pragma unroll
  for (int ti = 0; ti < 4; ti++) {
    #pragma unroll
    for (int tj = 0; tj < 4; tj++)
      #pragma unroll
      for (int r = 0; r < 4; r++)
        st[(quad * 4 + r) * 72 + tj * 16 + l16] = f2bf(acc[ti][tj][r]);
    // wave-local LDS RAW: in-order within a wave (verified pattern, r3 passed)
    #pragma unroll
    for (int h2 = 0; h2 < 2; h2++) {
      int rr = h2 * 8 + r2;
      int i = m0 + wm + ti * 16 + rr;
      int bb = i >> 12, ll = i & 4095;
      uint4 val = *reinterpret_cast<const uint4*>(&st[rr * 72 + c8]);
      *reinterpret_cast<uint4*>(&dbuf[(((size_t)(bb * 16 + hh)) * 4096 + ll) * 64 + c8]) = val;
    }
  }
}

// ---------------------------------------------------------------------------
// LayerNorm kernel (fallback path only; fast path fuses LN).
// ---------------------------------------------------------------------------
__global__ __launch_bounds__(256) void ln_k(short* __restrict__ kbuf)
{
  const int row = blockIdx.x * 4 + (threadIdx.x >> 6);
  const int lane = threadIdx.x & 63;
  const size_t idx = (size_t)row * 64 + lane;
  float v = bf2f(kbuf[idx]);
  float s = v, s2 = v * v;
  #pragma unroll
  for (int off = 32; off; off >>= 1) {
    s += __shfl_xor(s, off);
    s2 += __shfl_xor(s2, off);
  }
  float mean = s * (1.f / 64.f);
  float var = s2 * (1.f / 64.f) - mean * mean;
  float rstd = rsqrtf(var + EPS);
  kbuf[idx] = f2bf((v - mean) * rstd);
}

// ---------------------------------------------------------------------------
// Scan pass A: G[bh][c] = sum_t v[t,:] k_ln[t,:]^T with LN(k) fused.
// ---------------------------------------------------------------------------
__global__ __launch_bounds__(256) void chunk_outer(
    const short* __restrict__ kb, const short* __restrict__ vb,
    short* __restrict__ G)
{
  __shared__ __align__(16) short kT[64 * 72];
  __shared__ __align__(16) short vT[64 * 72];
  const int bh = blockIdx.x >> 6, c = blockIdx.x & 63;
  const int tid = threadIdx.x;
  const int w = tid >> 6, lane = tid & 63, quad = lane >> 4, l16 = lane & 15;
  const int srow = tid >> 2, sseg = (tid & 3) << 4;
  const size_t base = (size_t)bh * 262144 + (size_t)(c * 64 + srow) * 64 + sseg;

  {
    const float4* kp = reinterpret_cast<const float4*>(kb + base);
    union { float4 v[2]; short s[16]; } ku;
    ku.v[0] = kp[0]; ku.v[1] = kp[1];
    float kv[16]; float s = 0.f, s2 = 0.f;
    #pragma unroll
    for (int i = 0; i < 16; i++) { kv[i] = bf2f(ku.s[i]); s += kv[i]; s2 += kv[i] * kv[i]; }
    s += __shfl_xor(s, 1);  s2 += __shfl_xor(s2, 1);
    s += __shfl_xor(s, 2);  s2 += __shfl_xor(s2, 2);
    float mean = s * (1.f / 64.f);
    float var = s2 * (1.f / 64.f) - mean * mean;
    float rstd = rsqrtf(var + EPS);
    #pragma unroll
    for (int i = 0; i < 16; i++) kT[(sseg + i) * 72 + srow] = f2bf((kv[i] - mean) * rstd);
    const float4* vp = reinterpret_cast<const float4*>(vb + base);
    union { float4 v[2]; short s[16]; } vu;
    vu.v[0] = vp[0]; vu.v[1] = vp[1];
    #pragma unroll
    for (int i = 0; i < 16; i++) vT[(sseg + i) * 72 + srow] = vu.s[i];
  }
  __syncthreads();
  s16x8 va0 = *reinterpret_cast<const s16x8*>(&vT[(w * 16 + l16) * 72 + quad * 8]);
  s16x8 va1 = *reinterpret_cast<const s16x8*>(&vT[(w * 16 + l16) * 72 + 32 + quad * 8]);
  short* Gc = G + ((size_t)blockIdx.x) * 4096;
  #pragma unroll
  for (int tj = 0; tj < 4; tj++) {
    s16x8 kb0 = *reinterpret_cast<const s16x8*>(&kT[(tj * 16 + l16) * 72 + quad * 8]);
    s16x8 kb1 = *reinterpret_cast<const s16x8*>(&kT[(tj * 16 + l16) * 72 + 32 + quad * 8]);
    f4 z = {0.f, 0.f, 0.f, 0.f};
    z = __builtin_amdgcn_mfma_f32_16x16x32_bf16(va0, kb0, z, 0, 0, 0);
    z = __builtin_amdgcn_mfma_f32_16x16x32_bf16(va1, kb1, z, 0, 0, 0);
    #pragma unroll
    for (int r = 0; r < 4; r++)
      Gc[(w * 16 + quad * 4 + r) * 64 + tj * 16 + l16] = f2bf(z[r]);
  }
}

// ---------------------------------------------------------------------------
// Scan pass B: in-place exclusive prefix over c. 512 blocks x 128 threads.
// ---------------------------------------------------------------------------
__global__ __launch_bounds__(128) void prefix_S(short* __restrict__ G)
{
  const int bh = blockIdx.x >> 3, rg = blockIdx.x & 7;
  const size_t base = (size_t)bh * 262144 + rg * 512 + threadIdx.x * 4;
  float s0 = 0.f, s1 = 0.f, s2 = 0.f, s3 = 0.f;
  for (int c = 0; c < 64; c++) {
    short* p = G + base + (size_t)c * 4096;
    union { uint2 v; short s[4]; } gu;
    gu.v = *reinterpret_cast<const uint2*>(p);
    float g0 = bf2f(gu.s[0]), g1 = bf2f(gu.s[1]), g2 = bf2f(gu.s[2]), g3 = bf2f(gu.s[3]);
    union { uint2 v; short s[4]; } su;
    su.s[0] = f2bf(s0); su.s[1] = f2bf(s1); su.s[2] = f2bf(s2); su.s[3] = f2bf(s3);
    *reinterpret_cast<uint2*>(p) = su.v;
    s0 += g0; s1 += g1; s2 += g2; s3 += g3;
  }
}

// ---------------------------------------------------------------------------
// Scan pass C: y = tril(q k_ln^T) v + q S^T-contract, LN(k) fused in-reg.
// ---------------------------------------------------------------------------
__global__ __launch_bounds__(256) void chunk_out(
    const short* __restrict__ qb, const short* __restrict__ kb,
    const short* __restrict__ vb, const short* __restrict__ S,
    short* __restrict__ yb)
{
  __shared__ __align__(16) short vT[64 * 72];
  __shared__ __align__(16) short Ps[64 * 72];
  const int bh = blockIdx.x >> 6, c = blockIdx.x & 63;
  const int b = bh >> 4, h = bh & 15;
  const int tid = threadIdx.x;
  const int w = tid >> 6, lane = tid & 63, quad = lane >> 4, l16 = lane & 15;
  const int srow = tid >> 2, sseg = (tid & 3) << 4;
  const size_t base = (size_t)bh * 262144 + (size_t)c * 4096;

  {
    const float4* vp = reinterpret_cast<const float4*>(vb + base + (size_t)srow * 64 + sseg);
    union { float4 v[2]; short s[16]; } vu;
    vu.v[0] = vp[0]; vu.v[1] = vp[1];
    #pragma unroll
    for (int i = 0; i < 16; i++) vT[(sseg + i) * 72 + srow] = vu.s[i];
  }
  s16x8 qa[4][2], kf[2], sf[2];
  #pragma unroll
  for (int ti = 0; ti < 4; ti++)
    #pragma unroll
    for (int kh = 0; kh < 2; kh++)
      qa[ti][kh] = *reinterpret_cast<const s16x8*>(
          qb + base + (size_t)(ti * 16 + l16) * 64 + kh * 32 + quad * 8);
  #pragma unroll
  for (int kh = 0; kh < 2; kh++) {
    kf[kh] = *reinterpret_cast<const s16x8*>(
        kb + base + (size_t)(w * 16 + l16) * 64 + kh * 32 + quad * 8);
    sf[kh] = *reinterpret_cast<const s16x8*>(
        S + base + (size_t)(w * 16 + l16) * 64 + kh * 32 + quad * 8);
  }
  { // fused LN of k row (w*16+l16): row spread across lanes ^16, ^32
    float kv[16]; float s = 0.f, s2 = 0.f;
    #pragma unroll
    for (int kh = 0; kh < 2; kh++)
      #pragma unroll
      for (int i = 0; i < 8; i++) {
        float f = bf2f(kf[kh][i]); kv[kh * 8 + i] = f; s += f; s2 += f * f;
      }
    s += __shfl_xor(s, 16);  s2 += __shfl_xor(s2, 16);
    s += __shfl_xor(s, 32);  s2 += __shfl_xor(s2, 32);
    float mean = s * (1.f / 64.f);
    float var = s2 * (1.f / 64.f) - mean * mean;
    float rstd = rsqrtf(var + EPS);
    #pragma unroll
    for (int kh = 0; kh < 2; kh++)
      #pragma unroll
      for (int i = 0; i < 8; i++)
        kf[kh][i] = f2bf((kv[kh * 8 + i] - mean) * rstd);
  }
  __syncthreads();
  #pragma unroll
  for (int ti = 0; ti < 4; ti++) {
    f4 z = {0.f, 0.f, 0.f, 0.f};
    z = __builtin_amdgcn_mfma_f32_16x16x32_bf16(qa[ti][0], kf[0], z, 0, 0, 0);
    z = __builtin_amdgcn_mfma_f32_16x16x32_bf16(qa[ti][1], kf[1], z, 0, 0, 0);
    #pragma unroll
    for (int r = 0; r < 4; r++) {
      int t = ti * 16 + quad * 4 + r;
      int s = w * 16 + l16;
      Ps[t * 72 + s] = (s <= t) ? f2bf(z[r]) : (short)0;
    }
  }
  __syncthreads();
  s16x8 vf0 = *reinterpret_cast<const s16x8*>(&vT[(w * 16 + l16) * 72 + quad * 8]);
  s16x8 vf1 = *reinterpret_cast<const s16x8*>(&vT[(w * 16 + l16) * 72 + 32 + quad * 8]);
  #pragma unroll
  for (int ti = 0; ti < 4; ti++) {
    f4 z = {0.f, 0.f, 0.f, 0.f};
    s16x8 p0 = *reinterpret_cast<const s16x8*>(&Ps[(ti * 16 + l16) * 72 + quad * 8]);
    s16x8 p1 = *reinterpret_cast<const s16x8*>(&Ps[(ti * 16 + l16) * 72 + 32 + quad * 8]);
    z = __builtin_amdgcn_mfma_f32_16x16x32_bf16(p0, vf0, z, 0, 0, 0);
    z = __builtin_amdgcn_mfma_f32_16x16x32_bf16(p1, vf1, z, 0, 0, 0);
    z = __builtin_amdgcn_mfma_f32_16x16x32_bf16(qa[ti][0], sf[0], z, 0, 0, 0);
    z = __builtin_amdgcn_mfma_f32_16x16x32_bf16(qa[ti][1], sf[1], z, 0, 0, 0);
    #pragma unroll
    for (int r = 0; r < 4; r++) {
      int t = ti * 16 + quad * 4 + r;
      int d = w * 16 + l16;
      yb[(((size_t)b * 4096) + c * 64 + t) * 1024 + h * 64 + d] = f2bf(z[r]);
    }
  }
}

// ---------------------------------------------------------------------------
// GEMM2 v3: out = y(bf16) @ WoT^T, m97 structure + XCD swizzle.
// ---------------------------------------------------------------------------
__global__ __launch_bounds__(256) void gemm_out_v3(
    const short* __restrict__ A, const short* __restrict__ BT, float* __restrict__ C)
{
  __shared__ __align__(16) short As[128 * 32];
  __shared__ __align__(16) short Bs[128 * 32];
  const int p = blockIdx.x;          // 1024 blocks
  const int slot = p >> 3;
  const int strip = (p & 7) + 8 * (slot >> 3);
  const int nb = slot & 7;
  const int m0 = strip * 128, n0 = nb * 128;
  const int tid = threadIdx.x;
  const int w = tid >> 6, lane = tid & 63, quad = lane >> 4, l16 = lane & 15;
  const int wm = (w >> 1) << 6, wn = (w & 1) << 6;

  f4 acc[4][4];
  #pragma unroll
  for (int i = 0; i < 4; i++)
    #pragma unroll
    for (int j = 0; j < 4; j++) acc[i][j] = {0.f, 0.f, 0.f, 0.f};

  const int row = w * 32 + (lane >> 2), ofs = (lane & 3) << 3;

  for (int k0 = 0; k0 < 1024; k0 += 32) {
    __syncthreads();
    gll16(A + (size_t)(m0 + row) * 1024 + k0 + ofs, &As[(w * 32) * 32]);
    gll16(A + (size_t)(m0 + row + 16) * 1024 + k0 + ofs, &As[(w * 32 + 16) * 32]);
    gll16(BT + (size_t)(n0 + row) * 1024 + k0 + ofs, &Bs[(w * 32) * 32]);
    gll16(BT + (size_t)(n0 + row + 16) * 1024 + k0 + ofs, &Bs[(w * 32 + 16) * 32]);
    __syncthreads();
    s16x8 afr[4], bfr[4];
    #pragma unroll
    for (int t = 0; t < 4; t++)
      afr[t] = *reinterpret_cast<const s16x8*>(&As[(wm + t * 16 + l16) * 32 + quad * 8]);
    #pragma unroll
    for (int t = 0; t < 4; t++)
      bfr[t] = *reinterpret_cast<const s16x8*>(&Bs[(wn + t * 16 + l16) * 32 + quad * 8]);
    #pragma unroll
    for (int ti = 0; ti < 4; ti++)
      #pragma unroll
      for (int tj = 0; tj < 4; tj++)
        acc[ti][tj] = __builtin_amdgcn_mfma_f32_16x16x32_bf16(afr[ti], bfr[tj], acc[ti][tj], 0, 0, 0);
  }
  #pragma unroll
  for (int ti = 0; ti < 4; ti++)
    #pragma unroll
    for (int tj = 0; tj < 4; tj++)
      #pragma unroll
      for (int r = 0; r < 4; r++) {
        int i = m0 + wm + ti * 16 + quad * 4 + r;
        int j = n0 + wn + tj * 16 + l16;
        C[(size_t)i * 1024 + j] = acc[ti][tj][r];
      }
}

// ===========================================================================
// Fallback path (round-1 kernels) for small ws.
// ===========================================================================
__global__ __launch_bounds__(256) void gemm_qkv_r1(
    const float* __restrict__ A, const float* __restrict__ B,
    short* __restrict__ qb, short* __restrict__ kb, short* __restrict__ vb)
{
  __shared__ __align__(16) short As[128 * 40];
  __shared__ __align__(16) short Bs[128 * 40];
  const int n0 = blockIdx.x * 128;
  const int m0 = blockIdx.y * 128;
  const int tid = threadIdx.x;
  const int w = tid >> 6, lane = tid & 63, quad = lane >> 4, l16 = lane & 15;
  const int wm = (w >> 1) << 6, wn = (w & 1) << 6;
  f4 acc[4][4];
  #pragma unroll
  for (int i = 0; i < 4; i++)
    #pragma unroll
    for (int j = 0; j < 4; j++) acc[i][j] = {0.f, 0.f, 0.f, 0.f};
  const int arow = tid >> 1, aseg = (tid & 1) << 4;
  const int brow = tid >> 3, bseg = (tid & 7) << 4;
  for (int k0 = 0; k0 < 1024; k0 += 32) {
    __syncthreads();
    {
      const float4* ap = reinterpret_cast<const float4*>(A + (size_t)(m0 + arow) * 1024 + k0 + aseg);
      union { float4 v[4]; float f[16]; } af;
      af.v[0] = ap[0]; af.v[1] = ap[1]; af.v[2] = ap[2]; af.v[3] = ap[3];
      union { float4 v[2]; short s[16]; } ao;
      #pragma unroll
      for (int i = 0; i < 16; i++) ao.s[i] = f2bf(af.f[i]);
      float4* dst = reinterpret_cast<float4*>(&As[arow * 40 + aseg]);
      dst[0] = ao.v[0]; dst[1] = ao.v[1];
    }
    {
      const float4* bp = reinterpret_cast<const float4*>(B + (size_t)(k0 + brow) * 3072 + n0 + bseg);
      union { float4 v[4]; float f[16]; } bu;
      bu.v[0] = bp[0]; bu.v[1] = bp[1]; bu.v[2] = bp[2]; bu.v[3] = bp[3];
      #pragma unroll
      for (int i = 0; i < 16; i++) Bs[(bseg + i) * 40 + brow] = f2bf(bu.f[i]);
    }
    __syncthreads();
    s16x8 afr[4], bfr[4];
    #pragma unroll
    for (int t = 0; t < 4; t++)
      afr[t] = *reinterpret_cast<const s16x8*>(&As[(wm + t * 16 + l16) * 40 + quad * 8]);
    #pragma unroll
    for (int t = 0; t < 4; t++)
      bfr[t] = *reinterpret_cast<const s16x8*>(&Bs[(wn + t * 16 + l16) * 40 + quad * 8]);
    #pragma unroll
    for (int ti = 0; ti < 4; ti++)
      #pragma unroll
      for (int tj = 0; tj < 4; tj++)
        acc[ti][tj] = __builtin_amdgcn_mfma_f32_16x16x32_bf16(afr[ti], bfr[tj], acc[ti][tj], 0, 0, 0);
  }
  const int sq = n0 >> 10;
  short* dbuf = (sq == 0) ? qb : (sq == 1) ? kb : vb;
  #pragma unroll
  for (int ti = 0; ti < 4; ti++)
    #pragma unroll
    for (int tj = 0; tj < 4; tj++)
      #pragma unroll
      for (int r = 0; r < 4; r++) {
        int i = m0 + wm + ti * 16 + quad * 4 + r;
        int j = n0 + wn + tj * 16 + l16;
        int hh = (j >> 6) & 15, dd = j & 63;
        int bb = i >> 12, ll = i & 4095;
        dbuf[(((size_t)(bb * 16 + hh)) * 4096 + ll) * 64 + dd] = f2bf(acc[ti][tj][r]);
      }
}

__global__ __launch_bounds__(256) void scan_chunks_r1(
    const short* __restrict__ qb, const short* __restrict__ kb,
    const short* __restrict__ vb, short* __restrict__ yb)
{
  __shared__ __align__(16) short qs[64 * 72];
  __shared__ __align__(16) short ks[64 * 72];
  __shared__ __align__(16) short kT[64 * 72];
  __shared__ __align__(16) short vT[64 * 72];
  __shared__ __align__(16) short Sb[64 * 72];
  __shared__ __align__(16) short Ps[64 * 72];
  const int bh = blockIdx.x;
  const int b = bh >> 4, h = bh & 15;
  const int tid = threadIdx.x;
  const int w = tid >> 6, lane = tid & 63, quad = lane >> 4, l16 = lane & 15;
  const int srow = tid >> 2, sseg = (tid & 3) << 4;
  const size_t base = (size_t)bh * 4096 * 64;
  f4 accS[4];
  #pragma unroll
  for (int i = 0; i < 4; i++) accS[i] = {0.f, 0.f, 0.f, 0.f};
  for (int c = 0; c < 64; c++) {
    __syncthreads();
    {
      size_t g = base + ((size_t)(c * 64 + srow)) * 64 + sseg;
      const float4* qp = reinterpret_cast<const float4*>(qb + g);
      float4 q0 = qp[0], q1 = qp[1];
      *reinterpret_cast<float4*>(&qs[srow * 72 + sseg]) = q0;
      *reinterpret_cast<float4*>(&qs[srow * 72 + sseg + 8]) = q1;
      const float4* kp = reinterpret_cast<const float4*>(kb + g);
      union { float4 v[2]; short s[16]; } ku;
      ku.v[0] = kp[0]; ku.v[1] = kp[1];
      *reinterpret_cast<float4*>(&ks[srow * 72 + sseg]) = ku.v[0];
      *reinterpret_cast<float4*>(&ks[srow * 72 + sseg + 8]) = ku.v[1];
      #pragma unroll
      for (int i = 0; i < 16; i++) kT[(sseg + i) * 72 + srow] = ku.s[i];
      const float4* vp = reinterpret_cast<const float4*>(vb + g);
      union { float4 v[2]; short s[16]; } vu;
      vu.v[0] = vp[0]; vu.v[1] = vp[1];
      #pragma unroll
      for (int i = 0; i < 16; i++) vT[(sseg + i) * 72 + srow] = vu.s[i];
    }
    #pragma unroll
    for (int ti = 0; ti < 4; ti++)
      #pragma unroll
      for (int r = 0; r < 4; r++)
        Sb[(ti * 16 + quad * 4 + r) * 72 + w * 16 + l16] = f2bf(accS[ti][r]);
    __syncthreads();
    s16x8 qa[4][2];
    #pragma unroll
    for (int ti = 0; ti < 4; ti++)
      #pragma unroll
      for (int kh = 0; kh < 2; kh++)
        qa[ti][kh] = *reinterpret_cast<const s16x8*>(&qs[(ti * 16 + l16) * 72 + kh * 32 + quad * 8]);
    s16x8 kf[2];
    #pragma unroll
    for (int kh = 0; kh < 2; kh++)
      kf[kh] = *reinterpret_cast<const s16x8*>(&ks[(w * 16 + l16) * 72 + kh * 32 + quad * 8]);
    #pragma unroll
    for (int ti = 0; ti < 4; ti++) {
      f4 z = {0.f, 0.f, 0.f, 0.f};
      z = __builtin_amdgcn_mfma_f32_16x16x32_bf16(qa[ti][0], kf[0], z, 0, 0, 0);
      z = __builtin_amdgcn_mfma_f32_16x16x32_bf16(qa[ti][1], kf[1], z, 0, 0, 0);
      #pragma unroll
      for (int r = 0; r < 4; r++) {
        int t = ti * 16 + quad * 4 + r;
        int s = w * 16 + l16;
        Ps[t * 72 + s] = (s <= t) ? f2bf(z[r]) : (short)0;
      }
    }
    __syncthreads();
    s16x8 vf[2], sf[2];
    #pragma unroll
    for (int kh = 0; kh < 2; kh++) {
      vf[kh] = *reinterpret_cast<const s16x8*>(&vT[(w * 16 + l16) * 72 + kh * 32 + quad * 8]);
      sf[kh] = *reinterpret_cast<const s16x8*>(&Sb[(w * 16 + l16) * 72 + kh * 32 + quad * 8]);
    }
    #pragma unroll
    for (int ti = 0; ti < 4; ti++) {
      f4 z = {0.f, 0.f, 0.f, 0.f};
      s16x8 p0 = *reinterpret_cast<const s16x8*>(&Ps[(ti * 16 + l16) * 72 + quad * 8]);
      s16x8 p1 = *reinterpret_cast<const s16x8*>(&Ps[(ti * 16 + l16) * 72 + 32 + quad * 8]);
      z = __builtin_amdgcn_mfma_f32_16x16x32_bf16(p0, vf[0], z, 0, 0, 0);
      z = __builtin_amdgcn_mfma_f32_16x16x32_bf16(p1, vf[1], z, 0, 0, 0);
      z = __builtin_amdgcn_mfma_f32_16x16x32_bf16(qa[ti][0], sf[0], z, 0, 0, 0);
      z = __builtin_amdgcn_mfma_f32_16x16x32_bf16(qa[ti][1], sf[1], z, 0, 0, 0);
      #pragma unroll
      for (int r = 0; r < 4; r++) {
        int t = ti * 16 + quad * 4 + r;
        int d = w * 16 + l16;
        yb[(((size_t)b * 4096) + c * 64 + t) * 1024 + h * 64 + d] = f2bf(z[r]);
      }
    }
    s16x8 ku0 = *reinterpret_cast<const s16x8*>(&kT[(w * 16 + l16) * 72 + quad * 8]);
    s16x8 ku1 = *reinterpret_cast<const s16x8*>(&kT[(w * 16 + l16) * 72 + 32 + quad * 8]);
    #pragma unroll
    for (int ti = 0; ti < 4; ti++) {
      s16x8 va0 = *reinterpret_cast<const s16x8*>(&vT[(ti * 16 + l16) * 72 + quad * 8]);
      s16x8 va1 = *reinterpret_cast<const s16x8*>(&vT[(ti * 16 + l16) * 72 + 32 + quad * 8]);
      accS[ti] = __builtin_amdgcn_mfma_f32_16x16x32_bf16(va0, ku0, accS[ti], 0, 0, 0);
      accS[ti] = __builtin_amdgcn_mfma_f32_16x16x32_bf16(va1, ku1, accS[ti], 0, 0, 0);
    }
  }
}

__global__ __launch_bounds__(256) void gemm_out_r1(
    const short* __restrict__ A, const float* __restrict__ B, float* __restrict__ C)
{
  __shared__ __align__(16) short As[128 * 40];
  __shared__ __align__(16) short Bs[128 * 40];
  const int n0 = blockIdx.x * 128;
  const int m0 = blockIdx.y * 128;
  const int tid = threadIdx.x;
  const int w = tid >> 6, lane = tid & 63, quad = lane >> 4, l16 = lane & 15;
  const int wm = (w >> 1) << 6, wn = (w & 1) << 6;
  f4 acc[4][4];
  #pragma unroll
  for (int i = 0; i < 4; i++)
    #pragma unroll
    for (int j = 0; j < 4; j++) acc[i][j] = {0.f, 0.f, 0.f, 0.f};
  const int arow = tid >> 1, aseg = (tid & 1) << 4;
  const int brow = tid >> 3, bseg = (tid & 7) << 4;
  for (int k0 = 0; k0 < 1024; k0 += 32) {
    __syncthreads();
    {
      const float4* ap = reinterpret_cast<const float4*>(A + (size_t)(m0 + arow) * 1024 + k0 + aseg);
      float4 a0 = ap[0], a1 = ap[1];
      float4* dst = reinterpret_cast<float4*>(&As[arow * 40 + aseg]);
      dst[0] = a0; dst[1] = a1;
    }
    {
      const float4* bp = reinterpret_cast<const float4*>(B + (size_t)(k0 + brow) * 1024 + n0 + bseg);
      union { float4 v[4]; float f[16]; } bu;
      bu.v[0] = bp[0]; bu.v[1] = bp[1]; bu.v[2] = bp[2]; bu.v[3] = bp[3];
      #pragma unroll
      for (int i = 0; i < 16; i++) Bs[(bseg + i) * 40 + brow] = f2bf(bu.f[i]);
    }
    __syncthreads();
    s16x8 afr[4], bfr[4];
    #pragma unroll
    for (int t = 0; t < 4; t++)
      afr[t] = *reinterpret_cast<const s16x8*>(&As[(wm + t * 16 + l16) * 40 + quad * 8]);
    #pragma unroll
    for (int t = 0; t < 4; t++)
      bfr[t] = *reinterpret_cast<const s16x8*>(&Bs[(wn + t * 16 + l16) * 40 + quad * 8]);
    #pragma unroll
    for (int ti = 0; ti < 4; ti++)
      #pragma unroll
      for (int tj = 0; tj < 4; tj++)
        acc[ti][tj] = __builtin_amdgcn_mfma_f32_16x16x32_bf16(afr[ti], bfr[tj], acc[ti][tj], 0, 0, 0);
  }
  #pragma unroll
  for (int ti = 0; ti < 4; ti++)
    #pragma unroll
    for (int tj = 0; tj < 4; tj++)
      #pragma unroll
      for (int r = 0; r < 4; r++) {
        int i = m0 + wm + ti * 16 + quad * 4 + r;
        int j = n0 + wn + tj * 16 + l16;
        C[(size_t)i * 1024 + j] = acc[ti][tj][r];
      }
}

extern "C" void kernel_launch(void* const* d_in, const int* in_sizes, int n_in,
                              void* d_out, int out_size, void* d_ws, size_t ws_size,
                              hipStream_t stream) {
  const float* x    = (const float*)d_in[0];   // (4,4096,1024) fp32
  const float* Wqkv = (const float*)d_in[1];   // (1024,3072) fp32
  const float* Wo   = (const float*)d_in[2];   // (1024,1024) fp32
  float* out = (float*)d_out;                  // (4,4096,1024) fp32

  short* qb = (short*)d_ws;                    // 32 MB each region
  short* kb = qb + (size_t)16777216;
  short* vb = kb + (size_t)16777216;
  short* yb = vb + (size_t)16777216;

  const size_t NEED = 176160768;  // 168 MB fast-path footprint
  if (ws_size >= NEED) {
    short* Gs    = yb + (size_t)16777216;      // 32 MB: xb, then G/S (in-place)
    short* WqkvT = Gs + (size_t)16777216;      // 6 MB
    short* WoT   = WqkvT + (size_t)3145728;    // 2 MB
    short* xb    = Gs;                          // overlay: dead before chunk_outer

    prep          <<<dim3(12288),   256, 0, stream>>>(x, Wqkv, Wo, xb, WqkvT, WoT);
    gemm_qkv_v4   <<<dim3(3072),    256, 0, stream>>>(xb, WqkvT, qb, kb, vb);
    chunk_outer   <<<dim3(4096),    256, 0, stream>>>(kb, vb, Gs);
    prefix_S      <<<dim3(512),     128, 0, stream>>>(Gs);
    chunk_out     <<<dim3(4096),    256, 0, stream>>>(qb, kb, vb, Gs, yb);
    gemm_out_v3   <<<dim3(1024),    256, 0, stream>>>(yb, WoT, out);
  } else {
    gemm_qkv_r1   <<<dim3(24, 128), 256, 0, stream>>>(x, Wqkv, qb, kb, vb);
    ln_k          <<<dim3(65536),   256, 0, stream>>>(kb);
    scan_chunks_r1<<<dim3(64),      256, 0, stream>>>(qb, kb, vb, yb);
    gemm_out_r1   <<<dim3(8, 128),  256, 0, stream>>>(yb, Wo, out);
  }
}